// Round 8
// baseline (878.464 us; speedup 1.0000x reference)
//
#include <hip/hip_runtime.h>
#include <hip/hip_bf16.h>
#include <stdint.h>

#define B_ 32
#define T_ 12
#define N_ 1024
#define D_ 64
#define F_ 16
#define KH_ 8
#define BT_ (B_*T_)
#define NROWS_ (BT_*N_)
#define K3_ 3072

typedef unsigned short u16;
struct __align__(8) u16x4 { u16 x, y, z, w; };
struct __align__(16) u16x8 { u16 v[8]; };
typedef __attribute__((ext_vector_type(8))) short short8v;
typedef __attribute__((ext_vector_type(4))) float f32x4;

__device__ __forceinline__ float b2f(u16 u) {
  union { float f; unsigned int i; } c; c.i = ((unsigned int)u) << 16; return c.f;
}
__device__ __forceinline__ u16 f2b(float f) {
  union { float f; unsigned int i; } c; c.f = f;
  unsigned int u = c.i;
  unsigned int r = ((u >> 16) & 1u) + 0x7FFFu;
  return (u16)((u + r) >> 16);
}

__device__ __forceinline__ void gload_lds16(const void* g, void* l) {
  __builtin_amdgcn_global_load_lds(
      (const __attribute__((address_space(1))) unsigned int*)g,
      (__attribute__((address_space(3))) unsigned int*)l, 16, 0, 0);
}

// ---- K0: FEQ/FEK = relu(feat @ W) for both graphs. fe layout [4][1024][64]
__global__ void k_fe(const float* __restrict__ feat0, const float* __restrict__ feat1,
                     const float* __restrict__ Wq0, const float* __restrict__ Wk0,
                     const float* __restrict__ Wq1, const float* __restrict__ Wk1,
                     float* __restrict__ fe) {
  int r = blockIdx.x;
  int m = blockIdx.y;
  int d = threadIdx.x;
  const float* feat = (m < 2) ? feat0 : feat1;
  const float* W = (m == 0) ? Wq0 : (m == 1) ? Wk0 : (m == 2) ? Wq1 : Wk1;
  float acc = 0.f;
  #pragma unroll
  for (int f = 0; f < F_; ++f) acc += feat[r*F_ + f] * W[f*D_ + d];
  fe[((size_t)m*N_ + r)*D_ + d] = fmaxf(acc, 0.f);
}

// ---- K0b: copy adj into Acat[:, 0:1024] (bf16)
__global__ void k_adjcopy(const float* __restrict__ adj, u16* __restrict__ Acat) {
  int r = blockIdx.x;
  for (int c = threadIdx.x; c < N_; c += blockDim.x)
    Acat[(size_t)r*K3_ + c] = f2b(adj[(size_t)r*N_ + c]);
}

// ---- K0c: transpose small weights to bf16 [n][k] layouts (gridded, 64 blocks)
__global__ void k_prep(const float* __restrict__ Wq, const float* __restrict__ Wk,
                       const float* __restrict__ Wv,
                       const float* __restrict__ Wx1, const float* __restrict__ Wx2,
                       const float* __restrict__ Ws, const float* __restrict__ Wt,
                       const float* __restrict__ Wh1, const float* __restrict__ Wh2,
                       const float* __restrict__ Wgcn,
                       u16* __restrict__ Wqkvt, u16* __restrict__ W1t, u16* __restrict__ W2t,
                       u16* __restrict__ Wstt, u16* __restrict__ Wh1t, u16* __restrict__ Wh2t,
                       u16* __restrict__ Wgcnt) {
  int g0 = blockIdx.x*256 + threadIdx.x;
  const int stride = 64*256;
  for (int i = g0; i < 192*128; i += stride) {
    int nn = i >> 7, kk = i & 127;
    const float* W = (nn < 64) ? Wq : (nn < 128) ? Wk : Wv;
    Wqkvt[i] = f2b(W[kk*64 + (nn & 63)]);
  }
  for (int i = g0; i < 64*64; i += stride) {
    int nn = i >> 6, kk = i & 63;
    W1t[i] = f2b(Wx1[kk*64 + nn]);
    W2t[i] = f2b(Wx2[kk*64 + nn]);
    Wh1t[i] = f2b(Wh1[kk*64 + nn]);
    Wh2t[i] = f2b(Wh2[kk*64 + nn]);
  }
  for (int i = g0; i < 64*128; i += stride) {
    int nn = i >> 7, kk = i & 127;
    Wstt[i] = f2b((kk < 64) ? Ws[kk*64 + nn] : Wt[(kk-64)*64 + nn]);
  }
  for (int i = g0; i < 256*64; i += stride) {
    int cc = i >> 6, kk = i & 63;
    Wgcnt[i] = f2b(Wgcn[(size_t)((cc >> 6)*64 + kk)*64 + (cc & 63)]);
  }
}

// ---- K1: S_g = softmax(FEQ @ FEK^T / 8) rows -> Acat[:, 1024+g*1024 ...] (bf16)
__global__ __launch_bounds__(256) void k_graph_softmax(const float* __restrict__ fe,
                                                       u16* __restrict__ Acat) {
  int r = blockIdx.x, g = blockIdx.y;
  const float* FEQ = fe + (size_t)(g*2 + 0)*N_*D_;
  const float* FEK = fe + (size_t)(g*2 + 1)*N_*D_;
  __shared__ float q[D_];
  __shared__ float red[256];
  int tid = threadIdx.x;
  if (tid < D_) q[tid] = FEQ[(size_t)r*D_ + tid];
  __syncthreads();
  float lg[4];
  float mx = -1e30f;
  #pragma unroll
  for (int j = 0; j < 4; ++j) {
    int c = tid + j*256;
    const float* kr = FEK + (size_t)c*D_;
    float acc = 0.f;
    #pragma unroll
    for (int f = 0; f < D_; ++f) acc += q[f]*kr[f];
    lg[j] = acc * 0.125f;
    mx = fmaxf(mx, lg[j]);
  }
  red[tid] = mx; __syncthreads();
  for (int s = 128; s > 0; s >>= 1) { if (tid < s) red[tid] = fmaxf(red[tid], red[tid+s]); __syncthreads(); }
  mx = red[0]; __syncthreads();
  float sum = 0.f;
  #pragma unroll
  for (int j = 0; j < 4; ++j) { lg[j] = __expf(lg[j]-mx); sum += lg[j]; }
  red[tid] = sum; __syncthreads();
  for (int s = 128; s > 0; s >>= 1) { if (tid < s) red[tid] += red[tid+s]; __syncthreads(); }
  float inv = 1.f / red[0];
  #pragma unroll
  for (int j = 0; j < 4; ++j) {
    int c = tid + j*256;
    Acat[(size_t)r*K3_ + (1+g)*N_ + c] = f2b(lg[j]*inv);
  }
}

// ---- K2 (MFMA): [BTN,64] @ Wgcnt^T[64,256] -> G0 row-major + Yt1..3 transposed [bt][d][node]
__global__ __launch_bounds__(256) void k_xw_mfma(
    const float* __restrict__ X, const u16* __restrict__ Wgcnt,
    u16* __restrict__ G0, u16* __restrict__ Yt1, u16* __restrict__ Yt2, u16* __restrict__ Yt3)
{
  __shared__ __align__(16) u16 SM[24576];
  u16* Als = SM;
  u16* Bls = SM + 8192;
  u16* Tls = SM;
  u16* Gls = SM;
  int m0 = blockIdx.x * 128;
  int t = threadIdx.x;
  int w = t >> 6, l = t & 63;

  {
    int rsub = l >> 3, pch = l & 7;
    #pragma unroll
    for (int i = 0; i < 8; ++i) {
      int R0 = w*64 + i*8;
      int n = R0 + rsub;
      int q = pch ^ (n & 7);
      gload_lds16(Wgcnt + (size_t)n*64 + q*8, &Bls[R0*64]);
    }
  }
  #pragma unroll
  for (int i = 0; i < 4; ++i) {
    int flat = t + 256*i;
    int row = flat >> 3, c = flat & 7;
    const float* src = X + (size_t)(m0+row)*64 + c*8;
    float4 f0 = *(const float4*)src;
    float4 f1 = *(const float4*)(src + 4);
    u16x8 pk;
    pk.v[0]=f2b(f0.x); pk.v[1]=f2b(f0.y); pk.v[2]=f2b(f0.z); pk.v[3]=f2b(f0.w);
    pk.v[4]=f2b(f1.x); pk.v[5]=f2b(f1.y); pk.v[6]=f2b(f1.z); pk.v[7]=f2b(f1.w);
    int cs = c ^ (row & 7);
    *(u16x8*)&Als[row*64 + cs*8] = pk;
  }
  __syncthreads();

  int wm = w & 1, wn = w >> 1;
  int lr = l & 15, lk = l >> 4;
  f32x4 acc[4][8] = {};
  #pragma unroll
  for (int ks = 0; ks < 2; ++ks) {
    short8v av[4], bv[8];
    #pragma unroll
    for (int fm = 0; fm < 4; ++fm) {
      int r = wm*64 + fm*16 + lr;
      int ch = (ks*4 + lk) ^ (r & 7);
      av[fm] = *(const short8v*)&Als[r*64 + ch*8];
    }
    #pragma unroll
    for (int fn = 0; fn < 8; ++fn) {
      int n = wn*128 + fn*16 + lr;
      int ch = (ks*4 + lk) ^ (n & 7);
      bv[fn] = *(const short8v*)&Bls[n*64 + ch*8];
    }
    #pragma unroll
    for (int fm = 0; fm < 4; ++fm)
      #pragma unroll
      for (int fn = 0; fn < 8; ++fn)
        acc[fm][fn] = __builtin_amdgcn_mfma_f32_16x16x32_bf16(av[fm], bv[fn], acc[fm][fn], 0, 0, 0);
  }
  __syncthreads();

  #pragma unroll
  for (int fm = 0; fm < 4; ++fm) {
    int row0 = wm*64 + fm*16 + lk*4;
    #pragma unroll
    for (int fn = 0; fn < 8; ++fn) {
      int c = wn*128 + fn*16 + lr;
      if (c >= 64) {
        int dp = c - 64;
        u16x4 pk{ f2b(acc[fm][fn][0]), f2b(acc[fm][fn][1]),
                  f2b(acc[fm][fn][2]), f2b(acc[fm][fn][3]) };
        *(u16x4*)&Tls[dp*128 + (row0 ^ ((dp & 7) << 3))] = pk;
      }
    }
  }
  __syncthreads();
  {
    int bt = m0 >> 10, nb = m0 & 1023;
    #pragma unroll
    for (int i = 0; i < 12; ++i) {
      int cc = t + 256*i;
      int dp = cc >> 4, nc = cc & 15;
      int n0 = nc*8;
      u16x8 vv = *(const u16x8*)&Tls[dp*128 + (n0 ^ ((dp & 7) << 3))];
      int p = dp >> 6, d = dp & 63;
      u16* Yt = (p == 0) ? Yt1 : (p == 1) ? Yt2 : Yt3;
      *(u16x8*)&Yt[((size_t)bt*64 + d)*1024 + nb + n0] = vv;
    }
  }
  __syncthreads();

  if (wn == 0) {
    #pragma unroll
    for (int fm = 0; fm < 4; ++fm) {
      int row0 = wm*64 + fm*16 + lk*4;
      #pragma unroll
      for (int fn = 0; fn < 4; ++fn) {
        int c = fn*16 + lr;
        #pragma unroll
        for (int j = 0; j < 4; ++j) {
          int row = row0 + j;
          Gls[row*64 + (c ^ ((row & 7) << 3))] = f2b(acc[fm][fn][j]);
        }
      }
    }
  }
  __syncthreads();
  #pragma unroll
  for (int i = 0; i < 4; ++i) {
    int cc = t + 256*i;
    int row = cc >> 3, ch = cc & 7;
    u16x8 vv = *(const u16x8*)&Gls[row*64 + ((ch*8) ^ ((row & 7) << 3))];
    *(u16x8*)&G0[(size_t)(m0 + row)*64 + ch*8] = vv;
  }
}

// ---- K3 (MFMA): per bt-pair, C[128 node,128 (2bt x 64 d)] = Acat[128,3072] @ Bstack
// A: 3-buffer gload_lds + counted vmcnt. B: DIRECT global->register (L2-hot panel),
// register-double-buffered via manual x2 unroll. Removes the LDS-read BW bound.
#define BM 128
#define BK2 32
#define NKT2 (K3_/BK2)   // 96 (32 per plane)
__global__ __launch_bounds__(256) void k_spatial_mfma(
    const u16* __restrict__ Acat,
    const u16* __restrict__ Yt1, const u16* __restrict__ Yt2, const u16* __restrict__ Yt3,
    const float* __restrict__ bgcn,
    u16* __restrict__ HS)
{
  __shared__ __align__(16) u16 SM[16384];   // 32 KB; loop uses first 24 KB (3 x 8 KB A-buf)

  int f = blockIdx.x + 8*blockIdx.y;
  int u = f & 7, v = f >> 3;
  int btp = u*24 + (v >> 3);
  int m0  = (v & 7) * BM;
  int bt0 = btp * 2;

  int t = threadIdx.x;
  int w = t >> 6, l = t & 63;
  int rsub = l >> 2, pch = l & 3;

  f32x4 acc[4][4] = {};
  int wm = w >> 1, wn = w & 1;
  int lr = l & 15, lk = l >> 4;

  // A staging sources (slot p holds logical chunk p ^ ((row>>1)&3))
  const u16* aSrc[2];
  int R0s[2];
  #pragma unroll
  for (int i = 0; i < 2; ++i) {
    int row = w*32 + i*16 + rsub;
    int q = pch ^ ((row >> 1) & 3);
    aSrc[i] = Acat + (size_t)(m0 + row)*K3_ + q*8;
    R0s[i] = w*32 + i*16;
  }
  // B per-lane direct-load offsets (u32: max ~50 MB)
  unsigned rowOff[4];
  #pragma unroll
  for (int fn = 0; fn < 4; ++fn) {
    int n = wn*64 + fn*16 + lr;
    int bt = bt0 + (n >> 6), d = n & 63;
    rowOff[fn] = (unsigned)((bt*64 + d)*1024 + lk*8);
  }

  // prologue: stage A(0)->buf0, A(1)->buf1 (4 loads), THEN B(0) regs (ordering fence)
  #pragma unroll
  for (int s = 0; s < 2; ++s)
    #pragma unroll
    for (int i = 0; i < 2; ++i)
      gload_lds16(aSrc[i] + s*BK2, &SM[s*4096 + R0s[i]*32]);
  asm volatile("" ::: "memory");
  short8v bvA[4], bvB[4];
  #pragma unroll
  for (int fn = 0; fn < 4; ++fn) bvA[fn] = *(const short8v*)(Yt1 + rowOff[fn]);

  int s0 = 0;
  #pragma unroll 1
  for (int g = 0; g < NKT2; g += 2) {
    // ==== kt = g : consume bvA, prefetch bvB(g+1), stage A(g+2)
    {
      const int kt = g;
      if (kt >= NKT2 - 2) asm volatile("s_waitcnt vmcnt(0)" ::: "memory");
      else                asm volatile("s_waitcnt vmcnt(6)" ::: "memory");
      __builtin_amdgcn_s_barrier();
      asm volatile("" ::: "memory");
      const u16* A = SM + s0*4096;
      short8v av[4];
      #pragma unroll
      for (int fm = 0; fm < 4; ++fm) {
        int r = wm*64 + fm*16 + lr;
        int ch = lk ^ ((r >> 1) & 3);
        av[fm] = *(const short8v*)(A + r*32 + ch*8);
      }
      #pragma unroll
      for (int fm = 0; fm < 4; ++fm)
        #pragma unroll
        for (int fn = 0; fn < 4; ++fn)
          acc[fm][fn] = __builtin_amdgcn_mfma_f32_16x16x32_bf16(av[fm], bvA[fn], acc[fm][fn], 0, 0, 0);
      if (kt + 2 < NKT2) {
        int k2 = kt + 2;
        int sN = s0 + 2; if (sN >= 3) sN -= 3;
        #pragma unroll
        for (int i = 0; i < 2; ++i)
          gload_lds16(aSrc[i] + k2*BK2, &SM[sN*4096 + R0s[i]*32]);
      }
      {
        int k1 = kt + 1;
        const u16* Yt = (k1 < 32) ? Yt1 : (k1 < 64) ? Yt2 : Yt3;
        const u16* bb = Yt + (k1 & 31)*BK2;
        #pragma unroll
        for (int fn = 0; fn < 4; ++fn) bvB[fn] = *(const short8v*)(bb + rowOff[fn]);
      }
    }
    // ==== kt = g+1 : consume bvB, prefetch bvA(g+2), stage A(g+3)
    {
      const int kt = g + 1;
      int s1 = s0 + 1; if (s1 >= 3) s1 -= 3;
      if (kt >= NKT2 - 2) asm volatile("s_waitcnt vmcnt(0)" ::: "memory");
      else                asm volatile("s_waitcnt vmcnt(6)" ::: "memory");
      __builtin_amdgcn_s_barrier();
      asm volatile("" ::: "memory");
      const u16* A = SM + s1*4096;
      short8v av[4];
      #pragma unroll
      for (int fm = 0; fm < 4; ++fm) {
        int r = wm*64 + fm*16 + lr;
        int ch = lk ^ ((r >> 1) & 3);
        av[fm] = *(const short8v*)(A + r*32 + ch*8);
      }
      #pragma unroll
      for (int fm = 0; fm < 4; ++fm)
        #pragma unroll
        for (int fn = 0; fn < 4; ++fn)
          acc[fm][fn] = __builtin_amdgcn_mfma_f32_16x16x32_bf16(av[fm], bvB[fn], acc[fm][fn], 0, 0, 0);
      if (kt + 2 < NKT2) {
        int k2 = kt + 2;
        int sN = s1 + 2; if (sN >= 3) sN -= 3;
        #pragma unroll
        for (int i = 0; i < 2; ++i)
          gload_lds16(aSrc[i] + k2*BK2, &SM[sN*4096 + R0s[i]*32]);
      }
      if (kt + 1 < NKT2) {
        int k1 = kt + 1;
        const u16* Yt = (k1 < 32) ? Yt1 : (k1 < 64) ? Yt2 : Yt3;
        const u16* bb = Yt + (k1 & 31)*BK2;
        #pragma unroll
        for (int fn = 0; fn < 4; ++fn) bvA[fn] = *(const short8v*)(bb + rowOff[fn]);
      }
    }
    s0 += 2; if (s0 >= 3) s0 -= 3;
  }
  __syncthreads();

  // ---- epilogue: acc -> LDS transpose tile [128 node][128 col] (bf16, XOR-swizzled)
  u16* Tls = SM;
  #pragma unroll
  for (int fm = 0; fm < 4; ++fm) {
    #pragma unroll
    for (int fn = 0; fn < 4; ++fn) {
      int col = wn*64 + fn*16 + lr;
      int cc = col >> 3, cw = col & 7;
      #pragma unroll
      for (int j = 0; j < 4; ++j) {
        int node = wm*64 + fm*16 + lk*4 + j;
        int sc = cc ^ (node & 7);
        Tls[node*128 + sc*8 + cw] = f2b(acc[fm][fn][j]);
      }
    }
  }
  __syncthreads();
  #pragma unroll
  for (int i = 0; i < 8; ++i) {
    int flat = t + 256*i;
    int node = flat >> 4, cc = flat & 15;
    int sc = cc ^ (node & 7);
    u16x8 zv = *(const u16x8*)&Tls[node*128 + sc*8];
    int bt = bt0 + (cc >> 3), d0 = (cc & 7)*8;
    size_t idx = ((size_t)bt*N_ + (m0 + node))*64 + d0;
    u16x8 gv = *(const u16x8*)&HS[idx];
    float4 b0 = *(const float4*)&bgcn[d0];
    float4 b1 = *(const float4*)&bgcn[d0 + 4];
    float bb[8] = { b0.x, b0.y, b0.z, b0.w, b1.x, b1.y, b1.z, b1.w };
    u16x8 ov;
    #pragma unroll
    for (int e = 0; e < 8; ++e) {
      float vv2 = b2f(zv.v[e]) + b2f(gv.v[e]) + bb[e];
      ov.v[e] = f2b(fmaxf(vv2, 0.f));
    }
    *(u16x8*)&HS[idx] = ov;
  }
}

// ---- K4a (MFMA): qkv = relu([X|STE] @ Wqkv^T + b) -> q,k,v bf16 [BTN][64]
__global__ __launch_bounds__(256) void k_qkv(
    const float* __restrict__ X, const float* __restrict__ STE,
    const u16* __restrict__ Wqkvt,
    const float* __restrict__ bq, const float* __restrict__ bk, const float* __restrict__ bv,
    u16* __restrict__ qb, u16* __restrict__ kb, u16* __restrict__ vb)
{
  __shared__ __align__(16) u16 Als[128*128];   // [row][k], chunk-swizzled
  __shared__ __align__(16) u16 Bls[192*128];   // W^T [n][k], chunk-swizzled
  int m0 = blockIdx.x * 128;
  int t = threadIdx.x;
  int w = t >> 6, l = t & 63;

  {
    int rsub = l >> 4, pch = l & 15;
    #pragma unroll
    for (int i = 0; i < 12; ++i) {
      int R0 = w*48 + i*4;
      int n = R0 + rsub;
      int sq = pch ^ (n & 7);
      gload_lds16(Wqkvt + (size_t)n*128 + sq*8, &Bls[R0*128]);
    }
  }
  #pragma unroll
  for (int i = 0; i < 8; ++i) {
    int flat = t + 256*i;
    int row = flat >> 4, c = flat & 15;
    const float* src = ((c < 8) ? X : STE) + (size_t)(m0+row)*64 + (c & 7)*8;
    float4 f0 = *(const float4*)src;
    float4 f1 = *(const float4*)(src + 4);
    u16x8 pk;
    pk.v[0]=f2b(f0.x); pk.v[1]=f2b(f0.y); pk.v[2]=f2b(f0.z); pk.v[3]=f2b(f0.w);
    pk.v[4]=f2b(f1.x); pk.v[5]=f2b(f1.y); pk.v[6]=f2b(f1.z); pk.v[7]=f2b(f1.w);
    int cs = c ^ (row & 7);
    *(u16x8*)&Als[row*128 + cs*8] = pk;
  }
  __syncthreads();

  int wm = w >> 1, wn = w & 1;
  int lr = l & 15, lk = l >> 4;
  f32x4 acc[4][6] = {};
  #pragma unroll
  for (int ks = 0; ks < 4; ++ks) {
    short8v av[4], bvv[6];
    #pragma unroll
    for (int fm = 0; fm < 4; ++fm) {
      int r = wm*64 + fm*16 + lr;
      int ch = (ks*4 + lk) ^ (r & 7);
      av[fm] = *(const short8v*)&Als[r*128 + ch*8];
    }
    #pragma unroll
    for (int fn = 0; fn < 6; ++fn) {
      int n = wn*96 + fn*16 + lr;
      int ch = (ks*4 + lk) ^ (n & 7);
      bvv[fn] = *(const short8v*)&Bls[n*128 + ch*8];
    }
    #pragma unroll
    for (int fm = 0; fm < 4; ++fm)
      #pragma unroll
      for (int fn = 0; fn < 6; ++fn)
        acc[fm][fn] = __builtin_amdgcn_mfma_f32_16x16x32_bf16(av[fm], bvv[fn], acc[fm][fn], 0, 0, 0);
  }

  #pragma unroll
  for (int fm = 0; fm < 4; ++fm) {
    int rowb = m0 + wm*64 + fm*16 + lk*4;
    #pragma unroll
    for (int fn = 0; fn < 6; ++fn) {
      int col = wn*96 + fn*16 + lr;
      int sel = col >> 6, d = col & 63;
      u16* dst = (sel == 0) ? qb : (sel == 1) ? kb : vb;
      float bias = ((sel == 0) ? bq : (sel == 1) ? bk : bv)[d];
      #pragma unroll
      for (int j = 0; j < 4; ++j) {
        float val = acc[fm][fn][j] + bias;
        dst[(size_t)(rowb + j)*64 + d] = f2b(fmaxf(val, 0.f));
      }
    }
  }
}

// ---- K4b: attention only, one wave per (b,n), all-register, shuffle reduce
__global__ __launch_bounds__(256) void k_attn_lite(
    const u16* __restrict__ qb, const u16* __restrict__ kb, const u16* __restrict__ vb,
    u16* __restrict__ ob)
{
  int w = threadIdx.x >> 6, l = threadIdx.x & 63;
  int flat = blockIdx.x*4 + w;
  int b = flat >> 10, n = flat & 1023;
  float qv[T_], kv[T_], vv[T_];
  #pragma unroll
  for (int tt = 0; tt < T_; ++tt) {
    size_t idx = ((size_t)(b*T_ + tt)*N_ + n)*64 + l;
    qv[tt] = b2f(qb[idx]); kv[tt] = b2f(kb[idx]); vv[tt] = b2f(vb[idx]);
  }
  #pragma unroll
  for (int tt = 0; tt < T_; ++tt) {
    float sc[T_];
    float mx = -1e30f;
    #pragma unroll
    for (int j = 0; j < T_; ++j) {
      float p = qv[tt]*kv[j];
      p += __shfl_xor(p, 1);
      p += __shfl_xor(p, 2);
      p += __shfl_xor(p, 4);
      sc[j] = p * 0.3535533906f;
      mx = fmaxf(mx, sc[j]);
    }
    float sum = 0.f;
    #pragma unroll
    for (int j = 0; j < T_; ++j) { sc[j] = __expf(sc[j]-mx); sum += sc[j]; }
    float o = 0.f;
    #pragma unroll
    for (int j = 0; j < T_; ++j) o += sc[j]*vv[j];
    ob[((size_t)(b*T_ + tt)*N_ + n)*64 + l] = f2b(o / sum);
  }
}

// ---- K4c (MFMA): HT = relu(o@Wx1+bx1)@Wx2+bx2, chained in LDS
__global__ __launch_bounds__(256) void k_ht(
    const u16* __restrict__ ob, const u16* __restrict__ W1t, const u16* __restrict__ W2t,
    const float* __restrict__ bx1, const float* __restrict__ bx2,
    u16* __restrict__ HT)
{
  __shared__ __align__(16) u16 Ols[128*64];
  __shared__ __align__(16) u16 W1ls[64*64];
  __shared__ __align__(16) u16 W2ls[64*64];
  __shared__ __align__(16) u16 H1ls[128*64];
  int m0 = blockIdx.x * 128;
  int t = threadIdx.x;
  int w = t >> 6, l = t & 63;
  int rsub = l >> 3, pch = l & 7;

  #pragma unroll
  for (int i = 0; i < 4; ++i) {
    int R0 = w*32 + i*8;
    int row = R0 + rsub;
    int sq = pch ^ (row & 7);
    gload_lds16(ob + (size_t)(m0 + row)*64 + sq*8, &Ols[R0*64]);
  }
  #pragma unroll
  for (int i = 0; i < 2; ++i) {
    int R0 = w*16 + i*8;
    int row = R0 + rsub;
    int sq = pch ^ (row & 7);
    gload_lds16(W1t + (size_t)row*64 + sq*8, &W1ls[R0*64]);
    gload_lds16(W2t + (size_t)row*64 + sq*8, &W2ls[R0*64]);
  }
  __syncthreads();

  int wm = w >> 1, wn = w & 1;
  int lr = l & 15, lk = l >> 4;
  f32x4 acc1[4][2] = {};
  #pragma unroll
  for (int ks = 0; ks < 2; ++ks) {
    short8v av[4], bvv[2];
    #pragma unroll
    for (int fm = 0; fm < 4; ++fm) {
      int r = wm*64 + fm*16 + lr;
      int ch = (ks*4 + lk) ^ (r & 7);
      av[fm] = *(const short8v*)&Ols[r*64 + ch*8];
    }
    #pragma unroll
    for (int fn = 0; fn < 2; ++fn) {
      int n = wn*32 + fn*16 + lr;
      int ch = (ks*4 + lk) ^ (n & 7);
      bvv[fn] = *(const short8v*)&W1ls[n*64 + ch*8];
    }
    #pragma unroll
    for (int fm = 0; fm < 4; ++fm)
      #pragma unroll
      for (int fn = 0; fn < 2; ++fn)
        acc1[fm][fn] = __builtin_amdgcn_mfma_f32_16x16x32_bf16(av[fm], bvv[fn], acc1[fm][fn], 0, 0, 0);
  }
  #pragma unroll
  for (int fm = 0; fm < 4; ++fm) {
    #pragma unroll
    for (int fn = 0; fn < 2; ++fn) {
      int col = wn*32 + fn*16 + lr;
      float bias = bx1[col];
      #pragma unroll
      for (int j = 0; j < 4; ++j) {
        int row = wm*64 + fm*16 + lk*4 + j;
        float val = acc1[fm][fn][j] + bias;
        H1ls[row*64 + (((col >> 3) ^ (row & 7)))*8 + (col & 7)] = f2b(fmaxf(val, 0.f));
      }
    }
  }
  __syncthreads();

  f32x4 acc2[4][2] = {};
  #pragma unroll
  for (int ks = 0; ks < 2; ++ks) {
    short8v av[4], bvv[2];
    #pragma unroll
    for (int fm = 0; fm < 4; ++fm) {
      int r = wm*64 + fm*16 + lr;
      int ch = (ks*4 + lk) ^ (r & 7);
      av[fm] = *(const short8v*)&H1ls[r*64 + ch*8];
    }
    #pragma unroll
    for (int fn = 0; fn < 2; ++fn) {
      int n = wn*32 + fn*16 + lr;
      int ch = (ks*4 + lk) ^ (n & 7);
      bvv[fn] = *(const short8v*)&W2ls[n*64 + ch*8];
    }
    #pragma unroll
    for (int fm = 0; fm < 4; ++fm)
      #pragma unroll
      for (int fn = 0; fn < 2; ++fn)
        acc2[fm][fn] = __builtin_amdgcn_mfma_f32_16x16x32_bf16(av[fm], bvv[fn], acc2[fm][fn], 0, 0, 0);
  }
  #pragma unroll
  for (int fm = 0; fm < 4; ++fm) {
    #pragma unroll
    for (int fn = 0; fn < 2; ++fn) {
      int col = wn*32 + fn*16 + lr;
      float bias = bx2[col];
      #pragma unroll
      for (int j = 0; j < 4; ++j) {
        int row = wm*64 + fm*16 + lk*4 + j;
        HT[(size_t)(m0 + row)*64 + col] = f2b(acc2[fm][fn][j] + bias);
      }
    }
  }
}

// ---- K5 (MFMA): gated fusion + output head, 128 rows/block, all-LDS chain
__global__ __launch_bounds__(256) void k_fusion_mfma(
    const float* __restrict__ X,
    const u16* __restrict__ HS, const u16* __restrict__ HT,
    const u16* __restrict__ Wstt, const u16* __restrict__ Wh1t, const u16* __restrict__ Wh2t,
    const float* __restrict__ btb, const float* __restrict__ bh1, const float* __restrict__ bh2,
    float* __restrict__ out)
{
  __shared__ __align__(16) u16 Als[128*128];
  __shared__ __align__(16) u16 Wst[64*128];
  __shared__ __align__(16) u16 W1ls[64*64];
  __shared__ __align__(16) u16 W2ls[64*64];
  __shared__ __align__(16) u16 Hls[128*64];
  int m0 = blockIdx.x * 128;
  int t = threadIdx.x;
  int w = t >> 6, l = t & 63;

  {
    int rsub = l >> 4, pch = l & 15;
    #pragma unroll
    for (int i = 0; i < 8; ++i) {
      int R0 = w*32 + i*4;
      int row = R0 + rsub;
      int q = pch ^ (row & 7);
      const u16* src = (q < 8) ? (HS + (size_t)(m0 + row)*64 + q*8)
                               : (HT + (size_t)(m0 + row)*64 + (q - 8)*8);
      gload_lds16(src, &Als[R0*128]);
    }
    #pragma unroll
    for (int i = 0; i < 4; ++i) {
      int R0 = w*16 + i*4;
      int n = R0 + rsub;
      int q = pch ^ (n & 7);
      gload_lds16(Wstt + (size_t)n*128 + q*8, &Wst[R0*128]);
    }
  }
  {
    int rsub = l >> 3, pch = l & 7;
    #pragma unroll
    for (int i = 0; i < 2; ++i) {
      int R0 = w*16 + i*8;
      int row = R0 + rsub;
      int q = pch ^ (row & 7);
      gload_lds16(Wh1t + (size_t)row*64 + q*8, &W1ls[R0*64]);
      gload_lds16(Wh2t + (size_t)row*64 + q*8, &W2ls[R0*64]);
    }
  }
  __syncthreads();

  int lr = l & 15, lk = l >> 4;
  f32x4 acc1[2][4] = {};
  #pragma unroll
  for (int ks = 0; ks < 4; ++ks) {
    short8v av[2], bvv[4];
    #pragma unroll
    for (int fm = 0; fm < 2; ++fm) {
      int r = w*32 + fm*16 + lr;
      int ch = (ks*4 + lk) ^ (r & 7);
      av[fm] = *(const short8v*)&Als[r*128 + ch*8];
    }
    #pragma unroll
    for (int fn = 0; fn < 4; ++fn) {
      int n = fn*16 + lr;
      int ch = (ks*4 + lk) ^ (n & 7);
      bvv[fn] = *(const short8v*)&Wst[n*128 + ch*8];
    }
    #pragma unroll
    for (int fm = 0; fm < 2; ++fm)
      #pragma unroll
      for (int fn = 0; fn < 4; ++fn)
        acc1[fm][fn] = __builtin_amdgcn_mfma_f32_16x16x32_bf16(av[fm], bvv[fn], acc1[fm][fn], 0, 0, 0);
  }
  #pragma unroll
  for (int fm = 0; fm < 2; ++fm) {
    #pragma unroll
    for (int fn = 0; fn < 4; ++fn) {
      int col = fn*16 + lr;
      float bb = btb[col];
      #pragma unroll
      for (int j = 0; j < 4; ++j) {
        int row = w*32 + fm*16 + lk*4 + j;
        float a_s = acc1[fm][fn][j] + bb;
        float zg = 1.f/(1.f + __expf(-a_s));
        int cs = (col >> 3) ^ (row & 7);
        float hs = b2f(Als[row*128 + cs*8 + (col & 7)]);
        float ht = b2f(Als[row*128 + (cs + 8)*8 + (col & 7)]);
        float H = zg*hs + (1.f - zg)*ht;
        Hls[row*64 + cs*8 + (col & 7)] = f2b(H);
      }
    }
  }
  __syncthreads();

  u16* H2ls = Wst;
  f32x4 acc2[2][4] = {};
  #pragma unroll
  for (int ks = 0; ks < 2; ++ks) {
    short8v av[2], bvv[4];
    #pragma unroll
    for (int fm = 0; fm < 2; ++fm) {
      int r = w*32 + fm*16 + lr;
      int ch = (ks*4 + lk) ^ (r & 7);
      av[fm] = *(const short8v*)&Hls[r*64 + ch*8];
    }
    #pragma unroll
    for (int fn = 0; fn < 4; ++fn) {
      int n = fn*16 + lr;
      int ch = (ks*4 + lk) ^ (n & 7);
      bvv[fn] = *(const short8v*)&W1ls[n*64 + ch*8];
    }
    #pragma unroll
    for (int fm = 0; fm < 2; ++fm)
      #pragma unroll
      for (int fn = 0; fn < 4; ++fn)
        acc2[fm][fn] = __builtin_amdgcn_mfma_f32_16x16x32_bf16(av[fm], bvv[fn], acc2[fm][fn], 0, 0, 0);
  }
  __syncthreads();
  #pragma unroll
  for (int fm = 0; fm < 2; ++fm) {
    #pragma unroll
    for (int fn = 0; fn < 4; ++fn) {
      int col = fn*16 + lr;
      float bias = bh1[col];
      #pragma unroll
      for (int j = 0; j < 4; ++j) {
        int row = w*32 + fm*16 + lk*4 + j;
        float val = acc2[fm][fn][j] + bias;
        int cs = (col >> 3) ^ (row & 7);
        H2ls[row*64 + cs*8 + (col & 7)] = f2b(fmaxf(val, 0.f));
      }
    }
  }
  __syncthreads();

  f32x4 acc3[2][4] = {};
  #pragma unroll
  for (int ks = 0; ks < 2; ++ks) {
    short8v av[2], bvv[4];
    #pragma unroll
    for (int fm = 0; fm < 2; ++fm) {
      int r = w*32 + fm*16 + lr;
      int ch = (ks*4 + lk) ^ (r & 7);
      av[fm] = *(const short8v*)&H2ls[r*64 + ch*8];
    }
    #pragma unroll
    for (int fn = 0; fn < 4; ++fn) {
      int n = fn*16 + lr;
      int ch = (ks*4 + lk) ^ (n & 7);
      bvv[fn] = *(const short8v*)&W2ls[n*64 + ch*8];
    }
    #pragma unroll
    for (int fm = 0; fm < 2; ++fm)
      #pragma unroll
      for (int fn = 0; fn < 4; ++fn)
        acc3[fm][fn] = __builtin_amdgcn_mfma_f32_16x16x32_bf16(av[fm], bvv[fn], acc3[fm][fn], 0, 0, 0);
  }
  #pragma unroll
  for (int fm = 0; fm < 2; ++fm) {
    #pragma unroll
    for (int fn = 0; fn < 4; ++fn) {
      int col = fn*16 + lr;
      float bias = bh2[col];
      #pragma unroll
      for (int j = 0; j < 4; ++j) {
        int row = w*32 + fm*16 + lk*4 + j;
        size_t gi = (size_t)(m0 + row)*64 + col;
        out[gi] = X[gi] + acc3[fm][fn][j] + bias;
      }
    }
  }
}

extern "C" void kernel_launch(void* const* d_in, const int* in_sizes, int n_in,
                              void* d_out, int out_size, void* d_ws, size_t ws_size,
                              hipStream_t stream) {
  const float* X    = (const float*)d_in[0];
  const float* STE  = (const float*)d_in[1];
  const float* adj  = (const float*)d_in[2];
  const float* feat0= (const float*)d_in[3];
  const float* feat1= (const float*)d_in[4];
  const float* Wq0  = (const float*)d_in[5];
  const float* Wk0  = (const float*)d_in[6];
  const float* Wq1  = (const float*)d_in[7];
  const float* Wk1  = (const float*)d_in[8];
  const float* Wgcn = (const float*)d_in[9];
  const float* bgcn = (const float*)d_in[10];
  const float* Wq   = (const float*)d_in[11];
  const float* bq   = (const float*)d_in[12];
  const float* Wk   = (const float*)d_in[13];
  const float* bk   = (const float*)d_in[14];
  const float* Wv   = (const float*)d_in[15];
  const float* bv   = (const float*)d_in[16];
  const float* Wx1  = (const float*)d_in[17];
  const float* bx1  = (const float*)d_in[18];
  const float* Wx2  = (const float*)d_in[19];
  const float* bx2  = (const float*)d_in[20];
  const float* Ws   = (const float*)d_in[21];
  const float* Wt   = (const float*)d_in[22];
  const float* btb  = (const float*)d_in[23];
  const float* Wh1  = (const float*)d_in[24];
  const float* bh1  = (const float*)d_in[25];
  const float* Wh2  = (const float*)d_in[26];
  const float* bh2  = (const float*)d_in[27];
  (void)in_sizes; (void)n_in; (void)out_size;

  // ws layout: see R5 comment (unchanged)
  const size_t NEEDED = 164626432ull;
  if (ws_size < NEEDED) return;

  char* w = (char*)d_ws;
  float* fe    = (float*)(w);
  u16*   Acat  = (u16*)(w + 1048576);
  u16*   Wqkvt = (u16*)(w + 7340032);
  u16*   W1t   = (u16*)(w + 7389184);
  u16*   W2t   = (u16*)(w + 7397376);
  u16*   Wstt  = (u16*)(w + 7405568);
  u16*   Wh1t  = (u16*)(w + 7421952);
  u16*   Wh2t  = (u16*)(w + 7430144);
  u16*   Wgcnt = (u16*)(w + 7438336);
  u16*   Yt2   = (u16*)(w + 13631488);
  u16*   Yt3   = (u16*)(w + 63963136);
  u16*   HSb   = (u16*)(w + 114294784);
  u16*   Yt1   = (u16*)d_out;
  u16*   qb    = Yt2;
  u16*   kbuf  = Yt3;
  u16*   vbuf  = (u16*)d_out;
  u16*   obuf  = (u16*)d_out + (size_t)NROWS_*64;
  u16*   HTb   = Yt2;

  k_fe<<<dim3(N_, 4), 64, 0, stream>>>(feat0, feat1, Wq0, Wk0, Wq1, Wk1, fe);
  k_adjcopy<<<N_, 256, 0, stream>>>(adj, Acat);
  k_prep<<<64, 256, 0, stream>>>(Wq, Wk, Wv, Wx1, Wx2, Ws, Wt, Wh1, Wh2, Wgcn,
                                 Wqkvt, W1t, W2t, Wstt, Wh1t, Wh2t, Wgcnt);
  k_graph_softmax<<<dim3(N_, 2), 256, 0, stream>>>(fe, Acat);
  k_xw_mfma<<<NROWS_/128, 256, 0, stream>>>(X, Wgcnt, HSb, Yt1, Yt2, Yt3);
  k_spatial_mfma<<<dim3(8, BT_/2), 256, 0, stream>>>(Acat, Yt1, Yt2, Yt3, bgcn, HSb);
  k_qkv<<<NROWS_/128, 256, 0, stream>>>(X, STE, Wqkvt, bq, bk, bv, qb, kbuf, vbuf);
  k_attn_lite<<<(B_*N_)/4, 256, 0, stream>>>(qb, kbuf, vbuf, obuf);
  k_ht<<<NROWS_/128, 256, 0, stream>>>(obuf, W1t, W2t, bx1, bx2, HTb);
  k_fusion_mfma<<<NROWS_/128, 256, 0, stream>>>(X, HSb, HTb, Wstt, Wh1t, Wh2t,
                                                btb, bh1, bh2, (float*)d_out);
}

// Round 9
// 771.846 us; speedup vs baseline: 1.1381x; 1.1381x over previous
//
#include <hip/hip_runtime.h>
#include <hip/hip_bf16.h>
#include <stdint.h>

#define B_ 32
#define T_ 12
#define N_ 1024
#define D_ 64
#define F_ 16
#define KH_ 8
#define BT_ (B_*T_)
#define NROWS_ (BT_*N_)
#define K3_ 3072

typedef unsigned short u16;
struct __align__(8) u16x4 { u16 x, y, z, w; };
struct __align__(16) u16x8 { u16 v[8]; };
typedef __attribute__((ext_vector_type(8))) short short8v;
typedef __attribute__((ext_vector_type(4))) float f32x4;

__device__ __forceinline__ float b2f(u16 u) {
  union { float f; unsigned int i; } c; c.i = ((unsigned int)u) << 16; return c.f;
}
__device__ __forceinline__ u16 f2b(float f) {
  union { float f; unsigned int i; } c; c.f = f;
  unsigned int u = c.i;
  unsigned int r = ((u >> 16) & 1u) + 0x7FFFu;
  return (u16)((u + r) >> 16);
}

__device__ __forceinline__ void gload_lds16(const void* g, void* l) {
  __builtin_amdgcn_global_load_lds(
      (const __attribute__((address_space(1))) unsigned int*)g,
      (__attribute__((address_space(3))) unsigned int*)l, 16, 0, 0);
}

// ---- K0: FEQ/FEK = relu(feat @ W) for both graphs. fe layout [4][1024][64]
__global__ void k_fe(const float* __restrict__ feat0, const float* __restrict__ feat1,
                     const float* __restrict__ Wq0, const float* __restrict__ Wk0,
                     const float* __restrict__ Wq1, const float* __restrict__ Wk1,
                     float* __restrict__ fe) {
  int r = blockIdx.x;
  int m = blockIdx.y;
  int d = threadIdx.x;
  const float* feat = (m < 2) ? feat0 : feat1;
  const float* W = (m == 0) ? Wq0 : (m == 1) ? Wk0 : (m == 2) ? Wq1 : Wk1;
  float acc = 0.f;
  #pragma unroll
  for (int f = 0; f < F_; ++f) acc += feat[r*F_ + f] * W[f*D_ + d];
  fe[((size_t)m*N_ + r)*D_ + d] = fmaxf(acc, 0.f);
}

// ---- K0b: copy adj into Acat[:, 0:1024] (bf16)
__global__ void k_adjcopy(const float* __restrict__ adj, u16* __restrict__ Acat) {
  int r = blockIdx.x;
  for (int c = threadIdx.x; c < N_; c += blockDim.x)
    Acat[(size_t)r*K3_ + c] = f2b(adj[(size_t)r*N_ + c]);
}

// ---- K0c: transpose small weights to bf16 [n][k] layouts (gridded, 64 blocks)
__global__ void k_prep(const float* __restrict__ Wq, const float* __restrict__ Wk,
                       const float* __restrict__ Wv,
                       const float* __restrict__ Wx1, const float* __restrict__ Wx2,
                       const float* __restrict__ Ws, const float* __restrict__ Wt,
                       const float* __restrict__ Wh1, const float* __restrict__ Wh2,
                       const float* __restrict__ Wgcn,
                       u16* __restrict__ Wqkvt, u16* __restrict__ W1t, u16* __restrict__ W2t,
                       u16* __restrict__ Wstt, u16* __restrict__ Wh1t, u16* __restrict__ Wh2t,
                       u16* __restrict__ Wgcnt) {
  int g0 = blockIdx.x*256 + threadIdx.x;
  const int stride = 64*256;
  for (int i = g0; i < 192*128; i += stride) {
    int nn = i >> 7, kk = i & 127;
    const float* W = (nn < 64) ? Wq : (nn < 128) ? Wk : Wv;
    Wqkvt[i] = f2b(W[kk*64 + (nn & 63)]);
  }
  for (int i = g0; i < 64*64; i += stride) {
    int nn = i >> 6, kk = i & 63;
    W1t[i] = f2b(Wx1[kk*64 + nn]);
    W2t[i] = f2b(Wx2[kk*64 + nn]);
    Wh1t[i] = f2b(Wh1[kk*64 + nn]);
    Wh2t[i] = f2b(Wh2[kk*64 + nn]);
  }
  for (int i = g0; i < 64*128; i += stride) {
    int nn = i >> 7, kk = i & 127;
    Wstt[i] = f2b((kk < 64) ? Ws[kk*64 + nn] : Wt[(kk-64)*64 + nn]);
  }
  for (int i = g0; i < 256*64; i += stride) {
    int cc = i >> 6, kk = i & 63;
    Wgcnt[i] = f2b(Wgcn[(size_t)((cc >> 6)*64 + kk)*64 + (cc & 63)]);
  }
}

// ---- K1: S_g = softmax(FEQ @ FEK^T / 8) rows -> Acat[:, 1024+g*1024 ...] (bf16)
__global__ __launch_bounds__(256) void k_graph_softmax(const float* __restrict__ fe,
                                                       u16* __restrict__ Acat) {
  int r = blockIdx.x, g = blockIdx.y;
  const float* FEQ = fe + (size_t)(g*2 + 0)*N_*D_;
  const float* FEK = fe + (size_t)(g*2 + 1)*N_*D_;
  __shared__ float q[D_];
  __shared__ float red[256];
  int tid = threadIdx.x;
  if (tid < D_) q[tid] = FEQ[(size_t)r*D_ + tid];
  __syncthreads();
  float lg[4];
  float mx = -1e30f;
  #pragma unroll
  for (int j = 0; j < 4; ++j) {
    int c = tid + j*256;
    const float* kr = FEK + (size_t)c*D_;
    float acc = 0.f;
    #pragma unroll
    for (int f = 0; f < D_; ++f) acc += q[f]*kr[f];
    lg[j] = acc * 0.125f;
    mx = fmaxf(mx, lg[j]);
  }
  red[tid] = mx; __syncthreads();
  for (int s = 128; s > 0; s >>= 1) { if (tid < s) red[tid] = fmaxf(red[tid], red[tid+s]); __syncthreads(); }
  mx = red[0]; __syncthreads();
  float sum = 0.f;
  #pragma unroll
  for (int j = 0; j < 4; ++j) { lg[j] = __expf(lg[j]-mx); sum += lg[j]; }
  red[tid] = sum; __syncthreads();
  for (int s = 128; s > 0; s >>= 1) { if (tid < s) red[tid] += red[tid+s]; __syncthreads(); }
  float inv = 1.f / red[0];
  #pragma unroll
  for (int j = 0; j < 4; ++j) {
    int c = tid + j*256;
    Acat[(size_t)r*K3_ + (1+g)*N_ + c] = f2b(lg[j]*inv);
  }
}

// ---- K2 (MFMA): [BTN,64] @ Wgcnt^T[64,256] -> G0 row-major + Yt1..3 transposed [bt][d][node]
__global__ __launch_bounds__(256) void k_xw_mfma(
    const float* __restrict__ X, const u16* __restrict__ Wgcnt,
    u16* __restrict__ G0, u16* __restrict__ Yt1, u16* __restrict__ Yt2, u16* __restrict__ Yt3)
{
  __shared__ __align__(16) u16 SM[24576];
  u16* Als = SM;
  u16* Bls = SM + 8192;
  u16* Tls = SM;
  u16* Gls = SM;
  int m0 = blockIdx.x * 128;
  int t = threadIdx.x;
  int w = t >> 6, l = t & 63;

  {
    int rsub = l >> 3, pch = l & 7;
    #pragma unroll
    for (int i = 0; i < 8; ++i) {
      int R0 = w*64 + i*8;
      int n = R0 + rsub;
      int q = pch ^ (n & 7);
      gload_lds16(Wgcnt + (size_t)n*64 + q*8, &Bls[R0*64]);
    }
  }
  #pragma unroll
  for (int i = 0; i < 4; ++i) {
    int flat = t + 256*i;
    int row = flat >> 3, c = flat & 7;
    const float* src = X + (size_t)(m0+row)*64 + c*8;
    float4 f0 = *(const float4*)src;
    float4 f1 = *(const float4*)(src + 4);
    u16x8 pk;
    pk.v[0]=f2b(f0.x); pk.v[1]=f2b(f0.y); pk.v[2]=f2b(f0.z); pk.v[3]=f2b(f0.w);
    pk.v[4]=f2b(f1.x); pk.v[5]=f2b(f1.y); pk.v[6]=f2b(f1.z); pk.v[7]=f2b(f1.w);
    int cs = c ^ (row & 7);
    *(u16x8*)&Als[row*64 + cs*8] = pk;
  }
  __syncthreads();

  int wm = w & 1, wn = w >> 1;
  int lr = l & 15, lk = l >> 4;
  f32x4 acc[4][8] = {};
  #pragma unroll
  for (int ks = 0; ks < 2; ++ks) {
    short8v av[4], bv[8];
    #pragma unroll
    for (int fm = 0; fm < 4; ++fm) {
      int r = wm*64 + fm*16 + lr;
      int ch = (ks*4 + lk) ^ (r & 7);
      av[fm] = *(const short8v*)&Als[r*64 + ch*8];
    }
    #pragma unroll
    for (int fn = 0; fn < 8; ++fn) {
      int n = wn*128 + fn*16 + lr;
      int ch = (ks*4 + lk) ^ (n & 7);
      bv[fn] = *(const short8v*)&Bls[n*64 + ch*8];
    }
    #pragma unroll
    for (int fm = 0; fm < 4; ++fm)
      #pragma unroll
      for (int fn = 0; fn < 8; ++fn)
        acc[fm][fn] = __builtin_amdgcn_mfma_f32_16x16x32_bf16(av[fm], bv[fn], acc[fm][fn], 0, 0, 0);
  }
  __syncthreads();

  #pragma unroll
  for (int fm = 0; fm < 4; ++fm) {
    int row0 = wm*64 + fm*16 + lk*4;
    #pragma unroll
    for (int fn = 0; fn < 8; ++fn) {
      int c = wn*128 + fn*16 + lr;
      if (c >= 64) {
        int dp = c - 64;
        u16x4 pk{ f2b(acc[fm][fn][0]), f2b(acc[fm][fn][1]),
                  f2b(acc[fm][fn][2]), f2b(acc[fm][fn][3]) };
        *(u16x4*)&Tls[dp*128 + (row0 ^ ((dp & 7) << 3))] = pk;
      }
    }
  }
  __syncthreads();
  {
    int bt = m0 >> 10, nb = m0 & 1023;
    #pragma unroll
    for (int i = 0; i < 12; ++i) {
      int cc = t + 256*i;
      int dp = cc >> 4, nc = cc & 15;
      int n0 = nc*8;
      u16x8 vv = *(const u16x8*)&Tls[dp*128 + (n0 ^ ((dp & 7) << 3))];
      int p = dp >> 6, d = dp & 63;
      u16* Yt = (p == 0) ? Yt1 : (p == 1) ? Yt2 : Yt3;
      *(u16x8*)&Yt[((size_t)bt*64 + d)*1024 + nb + n0] = vv;
    }
  }
  __syncthreads();

  if (wn == 0) {
    #pragma unroll
    for (int fm = 0; fm < 4; ++fm) {
      int row0 = wm*64 + fm*16 + lk*4;
      #pragma unroll
      for (int fn = 0; fn < 4; ++fn) {
        int c = fn*16 + lr;
        #pragma unroll
        for (int j = 0; j < 4; ++j) {
          int row = row0 + j;
          Gls[row*64 + (c ^ ((row & 7) << 3))] = f2b(acc[fm][fn][j]);
        }
      }
    }
  }
  __syncthreads();
  #pragma unroll
  for (int i = 0; i < 4; ++i) {
    int cc = t + 256*i;
    int row = cc >> 3, ch = cc & 7;
    u16x8 vv = *(const u16x8*)&Gls[row*64 + ((ch*8) ^ ((row & 7) << 3))];
    *(u16x8*)&G0[(size_t)(m0 + row)*64 + ch*8] = vv;
  }
}

// ---- K3 (MFMA): per bt-QUAD, C[128 node, 256 (4bt x 64 d)] = Acat[128,3072] @ Bstack
// 4 waves of 64x128 (FLOP/LDS-byte 42.7 vs 32) + 3-buffer counted-vmcnt pipeline.
#define BM 128
#define BK2 32
#define NKT2 (K3_/BK2)   // 96 (32 per plane)
__global__ __launch_bounds__(256) void k_spatial_mfma(
    const u16* __restrict__ Acat,
    const u16* __restrict__ Yt1, const u16* __restrict__ Yt2, const u16* __restrict__ Yt3,
    const float* __restrict__ bgcn,
    u16* __restrict__ HS)
{
  __shared__ __align__(16) u16 SM[36864];   // 72 KB: 3 x (A 8KB + B 16KB)

  int f = blockIdx.x + 8*blockIdx.y;   // grid (8, 96) -> 0..767
  int u = f & 7, v = f >> 3;           // u ~ XCD, v 0..95
  int btq = u*12 + (v >> 3);           // bt-quad 0..95 (12 per XCD)
  int m0  = (v & 7) * BM;
  int bt0 = btq * 4;

  int t = threadIdx.x;
  int w = t >> 6, l = t & 63;
  int rsub = l >> 2, pch = l & 3;      // 16 rows x 4 chunks per gload group

  f32x4 acc[4][8] = {};
  int wm = w >> 1, wn = w & 1;         // wave tile: 64 rows x 128 cols
  int lr = l & 15, lk = l >> 4;

  // A staging sources (slot p holds logical chunk p ^ ((row>>1)&3))
  const u16* aSrc[2];
  int aR0[2];
  #pragma unroll
  for (int i = 0; i < 2; ++i) {
    int row = w*32 + i*16 + rsub;
    int q = pch ^ ((row >> 1) & 3);
    aSrc[i] = Acat + (size_t)(m0 + row)*K3_ + q*8;
    aR0[i] = w*32 + i*16;
  }
  // B staging sources: 256 rows (4bt x 64d)
  size_t bOff[4];
  int bR0[4];
  #pragma unroll
  for (int i = 0; i < 4; ++i) {
    int n = w*64 + i*16 + rsub;
    int q = pch ^ ((n >> 1) & 3);
    int bt = bt0 + (n >> 6), d = n & 63;
    bOff[i] = ((size_t)bt*64 + d)*1024 + q*8;
    bR0[i] = w*64 + i*16;
  }

  // prologue: stage kt=0 -> slot0, kt=1 -> slot1 (6 loads/thread each)
  #pragma unroll
  for (int s = 0; s < 2; ++s) {
    int kA = s*BK2;
    const u16* Yt = Yt1;               // kt 0,1 both in plane 0
    u16* base = SM + s*12288;
    #pragma unroll
    for (int i = 0; i < 2; ++i)
      gload_lds16(aSrc[i] + kA, base + aR0[i]*32);
    #pragma unroll
    for (int i = 0; i < 4; ++i)
      gload_lds16(Yt + bOff[i] + kA, base + 4096 + bR0[i]*32);
  }

  int s0 = 0;
  #pragma unroll 1
  for (int kt = 0; kt < NKT2; ++kt) {
    // wait for the OLDEST stage only (6 loads/stage in flight for kt+1)
    if (kt == NKT2 - 1) asm volatile("s_waitcnt vmcnt(0)" ::: "memory");
    else                asm volatile("s_waitcnt vmcnt(6)" ::: "memory");
    __builtin_amdgcn_s_barrier();
    asm volatile("" ::: "memory");

    const u16* A  = SM + s0*12288;
    const u16* Bp = A + 4096;
    short8v av[4], bv[8];
    #pragma unroll
    for (int fm = 0; fm < 4; ++fm) {
      int r = wm*64 + fm*16 + lr;
      int ch = lk ^ ((r >> 1) & 3);
      av[fm] = *(const short8v*)(A + r*32 + ch*8);
    }
    #pragma unroll
    for (int fn = 0; fn < 8; ++fn) {
      int n = wn*128 + fn*16 + lr;
      int ch = lk ^ ((n >> 1) & 3);
      bv[fn] = *(const short8v*)(Bp + n*32 + ch*8);
    }
    #pragma unroll
    for (int fm = 0; fm < 4; ++fm)
      #pragma unroll
      for (int fn = 0; fn < 8; ++fn)
        acc[fm][fn] = __builtin_amdgcn_mfma_f32_16x16x32_bf16(av[fm], bv[fn], acc[fm][fn], 0, 0, 0);

    // stage kt+2 into slot (s0+2)%3 (all reads of that slot finished before this barrier)
    if (kt + 2 < NKT2) {
      int k2 = kt + 2;
      int sN = s0 + 2; if (sN >= 3) sN -= 3;
      const u16* Yt = (k2 < 32) ? Yt1 : (k2 < 64) ? Yt2 : Yt3;
      int kA = k2*BK2, kB = (k2 & 31)*BK2;
      u16* base = SM + sN*12288;
      #pragma unroll
      for (int i = 0; i < 2; ++i)
        gload_lds16(aSrc[i] + kA, base + aR0[i]*32);
      #pragma unroll
      for (int i = 0; i < 4; ++i)
        gload_lds16(Yt + bOff[i] + kB, base + 4096 + bR0[i]*32);
    }
    ++s0; if (s0 >= 3) s0 -= 3;
  }
  __syncthreads();

  // ---- epilogue: acc -> LDS transpose tile [128 node][256 col] (bf16, XOR-swizzled)
  u16* Tls = SM;   // 128*256 u16 = 64 KB <= 72 KB
  #pragma unroll
  for (int fm = 0; fm < 4; ++fm) {
    #pragma unroll
    for (int fn = 0; fn < 8; ++fn) {
      int col = wn*128 + fn*16 + lr;
      int cc = col >> 3, cw = col & 7;
      #pragma unroll
      for (int j = 0; j < 4; ++j) {
        int node = wm*64 + fm*16 + lk*4 + j;
        int sc = cc ^ (node & 7);
        Tls[node*256 + sc*8 + cw] = f2b(acc[fm][fn][j]);
      }
    }
  }
  __syncthreads();
  // coalesced RMW: HS = relu(Z + G0 + bgcn), u16x8 granularity
  #pragma unroll
  for (int i = 0; i < 16; ++i) {
    int flat = t + 256*i;              // 0..4095 : 128 nodes x 32 chunks
    int node = flat >> 5, cc = flat & 31;
    int sc = cc ^ (node & 7);
    u16x8 zv = *(const u16x8*)&Tls[node*256 + sc*8];
    int bt = bt0 + (cc >> 3), d0 = (cc & 7)*8;
    size_t idx = ((size_t)bt*N_ + (m0 + node))*64 + d0;
    u16x8 gv = *(const u16x8*)&HS[idx];
    float4 b0 = *(const float4*)&bgcn[d0];
    float4 b1 = *(const float4*)&bgcn[d0 + 4];
    float bb[8] = { b0.x, b0.y, b0.z, b0.w, b1.x, b1.y, b1.z, b1.w };
    u16x8 ov;
    #pragma unroll
    for (int e = 0; e < 8; ++e) {
      float vv2 = b2f(zv.v[e]) + b2f(gv.v[e]) + bb[e];
      ov.v[e] = f2b(fmaxf(vv2, 0.f));
    }
    *(u16x8*)&HS[idx] = ov;
  }
}

// ---- K4a (MFMA): qkv = relu([X|STE] @ Wqkv^T + b) -> q,k,v bf16 [BTN][64]
__global__ __launch_bounds__(256) void k_qkv(
    const float* __restrict__ X, const float* __restrict__ STE,
    const u16* __restrict__ Wqkvt,
    const float* __restrict__ bq, const float* __restrict__ bk, const float* __restrict__ bv,
    u16* __restrict__ qb, u16* __restrict__ kb, u16* __restrict__ vb)
{
  __shared__ __align__(16) u16 Als[128*128];   // [row][k], chunk-swizzled
  __shared__ __align__(16) u16 Bls[192*128];   // W^T [n][k], chunk-swizzled
  int m0 = blockIdx.x * 128;
  int t = threadIdx.x;
  int w = t >> 6, l = t & 63;

  {
    int rsub = l >> 4, pch = l & 15;
    #pragma unroll
    for (int i = 0; i < 12; ++i) {
      int R0 = w*48 + i*4;
      int n = R0 + rsub;
      int sq = pch ^ (n & 7);
      gload_lds16(Wqkvt + (size_t)n*128 + sq*8, &Bls[R0*128]);
    }
  }
  #pragma unroll
  for (int i = 0; i < 8; ++i) {
    int flat = t + 256*i;
    int row = flat >> 4, c = flat & 15;
    const float* src = ((c < 8) ? X : STE) + (size_t)(m0+row)*64 + (c & 7)*8;
    float4 f0 = *(const float4*)src;
    float4 f1 = *(const float4*)(src + 4);
    u16x8 pk;
    pk.v[0]=f2b(f0.x); pk.v[1]=f2b(f0.y); pk.v[2]=f2b(f0.z); pk.v[3]=f2b(f0.w);
    pk.v[4]=f2b(f1.x); pk.v[5]=f2b(f1.y); pk.v[6]=f2b(f1.z); pk.v[7]=f2b(f1.w);
    int cs = c ^ (row & 7);
    *(u16x8*)&Als[row*128 + cs*8] = pk;
  }
  __syncthreads();

  int wm = w >> 1, wn = w & 1;
  int lr = l & 15, lk = l >> 4;
  f32x4 acc[4][6] = {};
  #pragma unroll
  for (int ks = 0; ks < 4; ++ks) {
    short8v av[4], bvv[6];
    #pragma unroll
    for (int fm = 0; fm < 4; ++fm) {
      int r = wm*64 + fm*16 + lr;
      int ch = (ks*4 + lk) ^ (r & 7);
      av[fm] = *(const short8v*)&Als[r*128 + ch*8];
    }
    #pragma unroll
    for (int fn = 0; fn < 6; ++fn) {
      int n = wn*96 + fn*16 + lr;
      int ch = (ks*4 + lk) ^ (n & 7);
      bvv[fn] = *(const short8v*)&Bls[n*128 + ch*8];
    }
    #pragma unroll
    for (int fm = 0; fm < 4; ++fm)
      #pragma unroll
      for (int fn = 0; fn < 6; ++fn)
        acc[fm][fn] = __builtin_amdgcn_mfma_f32_16x16x32_bf16(av[fm], bvv[fn], acc[fm][fn], 0, 0, 0);
  }

  #pragma unroll
  for (int fm = 0; fm < 4; ++fm) {
    int rowb = m0 + wm*64 + fm*16 + lk*4;
    #pragma unroll
    for (int fn = 0; fn < 6; ++fn) {
      int col = wn*96 + fn*16 + lr;
      int sel = col >> 6, d = col & 63;
      u16* dst = (sel == 0) ? qb : (sel == 1) ? kb : vb;
      float bias = ((sel == 0) ? bq : (sel == 1) ? bk : bv)[d];
      #pragma unroll
      for (int j = 0; j < 4; ++j) {
        float val = acc[fm][fn][j] + bias;
        dst[(size_t)(rowb + j)*64 + d] = f2b(fmaxf(val, 0.f));
      }
    }
  }
}

// ---- K4b: attention only, one wave per (b,n), all-register, shuffle reduce
__global__ __launch_bounds__(256) void k_attn_lite(
    const u16* __restrict__ qb, const u16* __restrict__ kb, const u16* __restrict__ vb,
    u16* __restrict__ ob)
{
  int w = threadIdx.x >> 6, l = threadIdx.x & 63;
  int flat = blockIdx.x*4 + w;
  int b = flat >> 10, n = flat & 1023;
  float qv[T_], kv[T_], vv[T_];
  #pragma unroll
  for (int tt = 0; tt < T_; ++tt) {
    size_t idx = ((size_t)(b*T_ + tt)*N_ + n)*64 + l;
    qv[tt] = b2f(qb[idx]); kv[tt] = b2f(kb[idx]); vv[tt] = b2f(vb[idx]);
  }
  #pragma unroll
  for (int tt = 0; tt < T_; ++tt) {
    float sc[T_];
    float mx = -1e30f;
    #pragma unroll
    for (int j = 0; j < T_; ++j) {
      float p = qv[tt]*kv[j];
      p += __shfl_xor(p, 1);
      p += __shfl_xor(p, 2);
      p += __shfl_xor(p, 4);
      sc[j] = p * 0.3535533906f;
      mx = fmaxf(mx, sc[j]);
    }
    float sum = 0.f;
    #pragma unroll
    for (int j = 0; j < T_; ++j) { sc[j] = __expf(sc[j]-mx); sum += sc[j]; }
    float o = 0.f;
    #pragma unroll
    for (int j = 0; j < T_; ++j) o += sc[j]*vv[j];
    ob[((size_t)(b*T_ + tt)*N_ + n)*64 + l] = f2b(o / sum);
  }
}

// ---- K4c (MFMA): HT = relu(o@Wx1+bx1)@Wx2+bx2, chained in LDS
__global__ __launch_bounds__(256) void k_ht(
    const u16* __restrict__ ob, const u16* __restrict__ W1t, const u16* __restrict__ W2t,
    const float* __restrict__ bx1, const float* __restrict__ bx2,
    u16* __restrict__ HT)
{
  __shared__ __align__(16) u16 Ols[128*64];
  __shared__ __align__(16) u16 W1ls[64*64];
  __shared__ __align__(16) u16 W2ls[64*64];
  __shared__ __align__(16) u16 H1ls[128*64];
  int m0 = blockIdx.x * 128;
  int t = threadIdx.x;
  int w = t >> 6, l = t & 63;
  int rsub = l >> 3, pch = l & 7;

  #pragma unroll
  for (int i = 0; i < 4; ++i) {
    int R0 = w*32 + i*8;
    int row = R0 + rsub;
    int sq = pch ^ (row & 7);
    gload_lds16(ob + (size_t)(m0 + row)*64 + sq*8, &Ols[R0*64]);
  }
  #pragma unroll
  for (int i = 0; i < 2; ++i) {
    int R0 = w*16 + i*8;
    int row = R0 + rsub;
    int sq = pch ^ (row & 7);
    gload_lds16(W1t + (size_t)row*64 + sq*8, &W1ls[R0*64]);
    gload_lds16(W2t + (size_t)row*64 + sq*8, &W2ls[R0*64]);
  }
  __syncthreads();

  int wm = w >> 1, wn = w & 1;
  int lr = l & 15, lk = l >> 4;
  f32x4 acc1[4][2] = {};
  #pragma unroll
  for (int ks = 0; ks < 2; ++ks) {
    short8v av[4], bvv[2];
    #pragma unroll
    for (int fm = 0; fm < 4; ++fm) {
      int r = wm*64 + fm*16 + lr;
      int ch = (ks*4 + lk) ^ (r & 7);
      av[fm] = *(const short8v*)&Ols[r*64 + ch*8];
    }
    #pragma unroll
    for (int fn = 0; fn < 2; ++fn) {
      int n = wn*32 + fn*16 + lr;
      int ch = (ks*4 + lk) ^ (n & 7);
      bvv[fn] = *(const short8v*)&W1ls[n*64 + ch*8];
    }
    #pragma unroll
    for (int fm = 0; fm < 4; ++fm)
      #pragma unroll
      for (int fn = 0; fn < 2; ++fn)
        acc1[fm][fn] = __builtin_amdgcn_mfma_f32_16x16x32_bf16(av[fm], bvv[fn], acc1[fm][fn], 0, 0, 0);
  }
  #pragma unroll
  for (int fm = 0; fm < 4; ++fm) {
    #pragma unroll
    for (int fn = 0; fn < 2; ++fn) {
      int col = wn*32 + fn*16 + lr;
      float bias = bx1[col];
      #pragma unroll
      for (int j = 0; j < 4; ++j) {
        int row = wm*64 + fm*16 + lk*4 + j;
        float val = acc1[fm][fn][j] + bias;
        H1ls[row*64 + (((col >> 3) ^ (row & 7)))*8 + (col & 7)] = f2b(fmaxf(val, 0.f));
      }
    }
  }
  __syncthreads();

  f32x4 acc2[4][2] = {};
  #pragma unroll
  for (int ks = 0; ks < 2; ++ks) {
    short8v av[4], bvv[2];
    #pragma unroll
    for (int fm = 0; fm < 4; ++fm) {
      int r = wm*64 + fm*16 + lr;
      int ch = (ks*4 + lk) ^ (r & 7);
      av[fm] = *(const short8v*)&H1ls[r*64 + ch*8];
    }
    #pragma unroll
    for (int fn = 0; fn < 2; ++fn) {
      int n = wn*32 + fn*16 + lr;
      int ch = (ks*4 + lk) ^ (n & 7);
      bvv[fn] = *(const short8v*)&W2ls[n*64 + ch*8];
    }
    #pragma unroll
    for (int fm = 0; fm < 4; ++fm)
      #pragma unroll
      for (int fn = 0; fn < 2; ++fn)
        acc2[fm][fn] = __builtin_amdgcn_mfma_f32_16x16x32_bf16(av[fm], bvv[fn], acc2[fm][fn], 0, 0, 0);
  }
  #pragma unroll
  for (int fm = 0; fm < 4; ++fm) {
    #pragma unroll
    for (int fn = 0; fn < 2; ++fn) {
      int col = wn*32 + fn*16 + lr;
      float bias = bx2[col];
      #pragma unroll
      for (int j = 0; j < 4; ++j) {
        int row = wm*64 + fm*16 + lk*4 + j;
        HT[(size_t)(m0 + row)*64 + col] = f2b(acc2[fm][fn][j] + bias);
      }
    }
  }
}

// ---- K5 (MFMA): gated fusion + output head, 128 rows/block, all-LDS chain
__global__ __launch_bounds__(256) void k_fusion_mfma(
    const float* __restrict__ X,
    const u16* __restrict__ HS, const u16* __restrict__ HT,
    const u16* __restrict__ Wstt, const u16* __restrict__ Wh1t, const u16* __restrict__ Wh2t,
    const float* __restrict__ btb, const float* __restrict__ bh1, const float* __restrict__ bh2,
    float* __restrict__ out)
{
  __shared__ __align__(16) u16 Als[128*128];
  __shared__ __align__(16) u16 Wst[64*128];
  __shared__ __align__(16) u16 W1ls[64*64];
  __shared__ __align__(16) u16 W2ls[64*64];
  __shared__ __align__(16) u16 Hls[128*64];
  int m0 = blockIdx.x * 128;
  int t = threadIdx.x;
  int w = t >> 6, l = t & 63;

  {
    int rsub = l >> 4, pch = l & 15;
    #pragma unroll
    for (int i = 0; i < 8; ++i) {
      int R0 = w*32 + i*4;
      int row = R0 + rsub;
      int q = pch ^ (row & 7);
      const u16* src = (q < 8) ? (HS + (size_t)(m0 + row)*64 + q*8)
                               : (HT + (size_t)(m0 + row)*64 + (q - 8)*8);
      gload_lds16(src, &Als[R0*128]);
    }
    #pragma unroll
    for (int i = 0; i < 4; ++i) {
      int R0 = w*16 + i*4;
      int n = R0 + rsub;
      int q = pch ^ (n & 7);
      gload_lds16(Wstt + (size_t)n*128 + q*8, &Wst[R0*128]);
    }
  }
  {
    int rsub = l >> 3, pch = l & 7;
    #pragma unroll
    for (int i = 0; i < 2; ++i) {
      int R0 = w*16 + i*8;
      int row = R0 + rsub;
      int q = pch ^ (row & 7);
      gload_lds16(Wh1t + (size_t)row*64 + q*8, &W1ls[R0*64]);
      gload_lds16(Wh2t + (size_t)row*64 + q*8, &W2ls[R0*64]);
    }
  }
  __syncthreads();

  int lr = l & 15, lk = l >> 4;
  f32x4 acc1[2][4] = {};
  #pragma unroll
  for (int ks = 0; ks < 4; ++ks) {
    short8v av[2], bvv[4];
    #pragma unroll
    for (int fm = 0; fm < 2; ++fm) {
      int r = w*32 + fm*16 + lr;
      int ch = (ks*4 + lk) ^ (r & 7);
      av[fm] = *(const short8v*)&Als[r*128 + ch*8];
    }
    #pragma unroll
    for (int fn = 0; fn < 4; ++fn) {
      int n = fn*16 + lr;
      int ch = (ks*4 + lk) ^ (n & 7);
      bvv[fn] = *(const short8v*)&Wst[n*128 + ch*8];
    }
    #pragma unroll
    for (int fm = 0; fm < 2; ++fm)
      #pragma unroll
      for (int fn = 0; fn < 4; ++fn)
        acc1[fm][fn] = __builtin_amdgcn_mfma_f32_16x16x32_bf16(av[fm], bvv[fn], acc1[fm][fn], 0, 0, 0);
  }
  #pragma unroll
  for (int fm = 0; fm < 2; ++fm) {
    #pragma unroll
    for (int fn = 0; fn < 4; ++fn) {
      int col = fn*16 + lr;
      float bb = btb[col];
      #pragma unroll
      for (int j = 0; j < 4; ++j) {
        int row = w*32 + fm*16 + lk*4 + j;
        float a_s = acc1[fm][fn][j] + bb;
        float zg = 1.f/(1.f + __expf(-a_s));
        int cs = (col >> 3) ^ (row & 7);
        float hs = b2f(Als[row*128 + cs*8 + (col & 7)]);
        float ht = b2f(Als[row*128 + (cs + 8)*8 + (col & 7)]);
        float H = zg*hs + (1.f - zg)*ht;
        Hls[row*64 + cs*8 + (col & 7)] = f2b(H);
      }
    }
  }
  __syncthreads();

  u16* H2ls = Wst;
  f32x4 acc2[2][4] = {};
  #pragma unroll
  for (int ks = 0; ks < 2; ++ks) {
    short8v av[2], bvv[4];
    #pragma unroll
    for (int fm = 0; fm < 2; ++fm) {
      int r = w*32 + fm*16 + lr;
      int ch = (ks*4 + lk) ^ (r & 7);
      av[fm] = *(const short8v*)&Hls[r*64 + ch*8];
    }
    #pragma unroll
    for (int fn = 0; fn < 4; ++fn) {
      int n = fn*16 + lr;
      int ch = (ks*4 + lk) ^ (n & 7);
      bvv[fn] = *(const short8v*)&W1ls[n*64 + ch*8];
    }
    #pragma unroll
    for (int fm = 0; fm < 2; ++fm)
      #pragma unroll
      for (int fn = 0; fn < 4; ++fn)
        acc2[fm][fn] = __builtin_amdgcn_mfma_f32_16x16x32_bf16(av[fm], bvv[fn], acc2[fm][fn], 0, 0, 0);
  }
  __syncthreads();
  #pragma unroll
  for (int fm = 0; fm < 2; ++fm) {
    #pragma unroll
    for (int fn = 0; fn < 4; ++fn) {
      int col = fn*16 + lr;
      float bias = bh1[col];
      #pragma unroll
      for (int j = 0; j < 4; ++j) {
        int row = w*32 + fm*16 + lk*4 + j;
        float val = acc2[fm][fn][j] + bias;
        int cs = (col >> 3) ^ (row & 7);
        H2ls[row*64 + cs*8 + (col & 7)] = f2b(fmaxf(val, 0.f));
      }
    }
  }
  __syncthreads();

  f32x4 acc3[2][4] = {};
  #pragma unroll
  for (int ks = 0; ks < 2; ++ks) {
    short8v av[2], bvv[4];
    #pragma unroll
    for (int fm = 0; fm < 2; ++fm) {
      int r = w*32 + fm*16 + lr;
      int ch = (ks*4 + lk) ^ (r & 7);
      av[fm] = *(const short8v*)&H2ls[r*64 + ch*8];
    }
    #pragma unroll
    for (int fn = 0; fn < 4; ++fn) {
      int n = fn*16 + lr;
      int ch = (ks*4 + lk) ^ (n & 7);
      bvv[fn] = *(const short8v*)&W2ls[n*64 + ch*8];
    }
    #pragma unroll
    for (int fm = 0; fm < 2; ++fm)
      #pragma unroll
      for (int fn = 0; fn < 4; ++fn)
        acc3[fm][fn] = __builtin_amdgcn_mfma_f32_16x16x32_bf16(av[fm], bvv[fn], acc3[fm][fn], 0, 0, 0);
  }
  #pragma unroll
  for (int fm = 0; fm < 2; ++fm) {
    #pragma unroll
    for (int fn = 0; fn < 4; ++fn) {
      int col = fn*16 + lr;
      float bias = bh2[col];
      #pragma unroll
      for (int j = 0; j < 4; ++j) {
        int row = w*32 + fm*16 + lk*4 + j;
        size_t gi = (size_t)(m0 + row)*64 + col;
        out[gi] = X[gi] + acc3[fm][fn][j] + bias;
      }
    }
  }
}

extern "C" void kernel_launch(void* const* d_in, const int* in_sizes, int n_in,
                              void* d_out, int out_size, void* d_ws, size_t ws_size,
                              hipStream_t stream) {
  const float* X    = (const float*)d_in[0];
  const float* STE  = (const float*)d_in[1];
  const float* adj  = (const float*)d_in[2];
  const float* feat0= (const float*)d_in[3];
  const float* feat1= (const float*)d_in[4];
  const float* Wq0  = (const float*)d_in[5];
  const float* Wk0  = (const float*)d_in[6];
  const float* Wq1  = (const float*)d_in[7];
  const float* Wk1  = (const float*)d_in[8];
  const float* Wgcn = (const float*)d_in[9];
  const float* bgcn = (const float*)d_in[10];
  const float* Wq   = (const float*)d_in[11];
  const float* bq   = (const float*)d_in[12];
  const float* Wk   = (const float*)d_in[13];
  const float* bk   = (const float*)d_in[14];
  const float* Wv   = (const float*)d_in[15];
  const float* bv   = (const float*)d_in[16];
  const float* Wx1  = (const float*)d_in[17];
  const float* bx1  = (const float*)d_in[18];
  const float* Wx2  = (const float*)d_in[19];
  const float* bx2  = (const float*)d_in[20];
  const float* Ws   = (const float*)d_in[21];
  const float* Wt   = (const float*)d_in[22];
  const float* btb  = (const float*)d_in[23];
  const float* Wh1  = (const float*)d_in[24];
  const float* bh1  = (const float*)d_in[25];
  const float* Wh2  = (const float*)d_in[26];
  const float* bh2  = (const float*)d_in[27];
  (void)in_sizes; (void)n_in; (void)out_size;

  // ws layout: see R5 comment (unchanged)
  const size_t NEEDED = 164626432ull;
  if (ws_size < NEEDED) return;

  char* w = (char*)d_ws;
  float* fe    = (float*)(w);
  u16*   Acat  = (u16*)(w + 1048576);
  u16*   Wqkvt = (u16*)(w + 7340032);
  u16*   W1t   = (u16*)(w + 7389184);
  u16*   W2t   = (u16*)(w + 7397376);
  u16*   Wstt  = (u16*)(w + 7405568);
  u16*   Wh1t  = (u16*)(w + 7421952);
  u16*   Wh2t  = (u16*)(w + 7430144);
  u16*   Wgcnt = (u16*)(w + 7438336);
  u16*   Yt2   = (u16*)(w + 13631488);
  u16*   Yt3   = (u16*)(w + 63963136);
  u16*   HSb   = (u16*)(w + 114294784);
  u16*   Yt1   = (u16*)d_out;
  u16*   qb    = Yt2;
  u16*   kbuf  = Yt3;
  u16*   vbuf  = (u16*)d_out;
  u16*   obuf  = (u16*)d_out + (size_t)NROWS_*64;
  u16*   HTb   = Yt2;

  k_fe<<<dim3(N_, 4), 64, 0, stream>>>(feat0, feat1, Wq0, Wk0, Wq1, Wk1, fe);
  k_adjcopy<<<N_, 256, 0, stream>>>(adj, Acat);
  k_prep<<<64, 256, 0, stream>>>(Wq, Wk, Wv, Wx1, Wx2, Ws, Wt, Wh1, Wh2, Wgcn,
                                 Wqkvt, W1t, W2t, Wstt, Wh1t, Wh2t, Wgcnt);
  k_graph_softmax<<<dim3(N_, 2), 256, 0, stream>>>(fe, Acat);
  k_xw_mfma<<<NROWS_/128, 256, 0, stream>>>(X, Wgcnt, HSb, Yt1, Yt2, Yt3);
  k_spatial_mfma<<<dim3(8, BT_/4), 256, 0, stream>>>(Acat, Yt1, Yt2, Yt3, bgcn, HSb);
  k_qkv<<<NROWS_/128, 256, 0, stream>>>(X, STE, Wqkvt, bq, bk, bv, qb, kbuf, vbuf);
  k_attn_lite<<<(B_*N_)/4, 256, 0, stream>>>(qb, kbuf, vbuf, obuf);
  k_ht<<<NROWS_/128, 256, 0, stream>>>(obuf, W1t, W2t, bx1, bx2, HTb);
  k_fusion_mfma<<<NROWS_/128, 256, 0, stream>>>(X, HSb, HTb, Wstt, Wh1t, Wh2t,
                                                btb, bh1, bh2, (float*)d_out);
}

// Round 10
// 725.340 us; speedup vs baseline: 1.2111x; 1.0641x over previous
//
#include <hip/hip_runtime.h>
#include <hip/hip_bf16.h>
#include <stdint.h>

#define B_ 32
#define T_ 12
#define N_ 1024
#define D_ 64
#define F_ 16
#define KH_ 8
#define BT_ (B_*T_)
#define NROWS_ (BT_*N_)
#define K3_ 3072

typedef unsigned short u16;
struct __align__(8) u16x4 { u16 x, y, z, w; };
struct __align__(16) u16x8 { u16 v[8]; };
typedef __attribute__((ext_vector_type(8))) short short8v;
typedef __attribute__((ext_vector_type(4))) float f32x4;

__device__ __forceinline__ float b2f(u16 u) {
  union { float f; unsigned int i; } c; c.i = ((unsigned int)u) << 16; return c.f;
}
__device__ __forceinline__ u16 f2b(float f) {
  union { float f; unsigned int i; } c; c.f = f;
  unsigned int u = c.i;
  unsigned int r = ((u >> 16) & 1u) + 0x7FFFu;
  return (u16)((u + r) >> 16);
}

__device__ __forceinline__ void gload_lds16(const void* g, void* l) {
  __builtin_amdgcn_global_load_lds(
      (const __attribute__((address_space(1))) unsigned int*)g,
      (__attribute__((address_space(3))) unsigned int*)l, 16, 0, 0);
}

// ---- K0: FEQ/FEK = relu(feat @ W) for both graphs. fe layout [4][1024][64]
__global__ void k_fe(const float* __restrict__ feat0, const float* __restrict__ feat1,
                     const float* __restrict__ Wq0, const float* __restrict__ Wk0,
                     const float* __restrict__ Wq1, const float* __restrict__ Wk1,
                     float* __restrict__ fe) {
  int r = blockIdx.x;
  int m = blockIdx.y;
  int d = threadIdx.x;
  const float* feat = (m < 2) ? feat0 : feat1;
  const float* W = (m == 0) ? Wq0 : (m == 1) ? Wk0 : (m == 2) ? Wq1 : Wk1;
  float acc = 0.f;
  #pragma unroll
  for (int f = 0; f < F_; ++f) acc += feat[r*F_ + f] * W[f*D_ + d];
  fe[((size_t)m*N_ + r)*D_ + d] = fmaxf(acc, 0.f);
}

// ---- K0b: copy adj into Acat[:, 0:1024] (bf16)
__global__ void k_adjcopy(const float* __restrict__ adj, u16* __restrict__ Acat) {
  int r = blockIdx.x;
  for (int c = threadIdx.x; c < N_; c += blockDim.x)
    Acat[(size_t)r*K3_ + c] = f2b(adj[(size_t)r*N_ + c]);
}

// ---- K0c: transpose small weights to bf16 [n][k] layouts (gridded, 64 blocks)
__global__ void k_prep(const float* __restrict__ Wq, const float* __restrict__ Wk,
                       const float* __restrict__ Wv,
                       const float* __restrict__ Wx1, const float* __restrict__ Wx2,
                       const float* __restrict__ Ws, const float* __restrict__ Wt,
                       const float* __restrict__ Wh1, const float* __restrict__ Wh2,
                       const float* __restrict__ Wgcn,
                       u16* __restrict__ Wqkvt, u16* __restrict__ W1t, u16* __restrict__ W2t,
                       u16* __restrict__ Wstt, u16* __restrict__ Wh1t, u16* __restrict__ Wh2t,
                       u16* __restrict__ Wgcnt) {
  int g0 = blockIdx.x*256 + threadIdx.x;
  const int stride = 64*256;
  for (int i = g0; i < 192*128; i += stride) {
    int nn = i >> 7, kk = i & 127;
    const float* W = (nn < 64) ? Wq : (nn < 128) ? Wk : Wv;
    Wqkvt[i] = f2b(W[kk*64 + (nn & 63)]);
  }
  for (int i = g0; i < 64*64; i += stride) {
    int nn = i >> 6, kk = i & 63;
    W1t[i] = f2b(Wx1[kk*64 + nn]);
    W2t[i] = f2b(Wx2[kk*64 + nn]);
    Wh1t[i] = f2b(Wh1[kk*64 + nn]);
    Wh2t[i] = f2b(Wh2[kk*64 + nn]);
  }
  for (int i = g0; i < 64*128; i += stride) {
    int nn = i >> 7, kk = i & 127;
    Wstt[i] = f2b((kk < 64) ? Ws[kk*64 + nn] : Wt[(kk-64)*64 + nn]);
  }
  for (int i = g0; i < 256*64; i += stride) {
    int cc = i >> 6, kk = i & 63;
    Wgcnt[i] = f2b(Wgcn[(size_t)((cc >> 6)*64 + kk)*64 + (cc & 63)]);
  }
}

// ---- K1: S_g = softmax(FEQ @ FEK^T / 8) rows -> Acat[:, 1024+g*1024 ...] (bf16)
__global__ __launch_bounds__(256) void k_graph_softmax(const float* __restrict__ fe,
                                                       u16* __restrict__ Acat) {
  int r = blockIdx.x, g = blockIdx.y;
  const float* FEQ = fe + (size_t)(g*2 + 0)*N_*D_;
  const float* FEK = fe + (size_t)(g*2 + 1)*N_*D_;
  __shared__ float q[D_];
  __shared__ float red[256];
  int tid = threadIdx.x;
  if (tid < D_) q[tid] = FEQ[(size_t)r*D_ + tid];
  __syncthreads();
  float lg[4];
  float mx = -1e30f;
  #pragma unroll
  for (int j = 0; j < 4; ++j) {
    int c = tid + j*256;
    const float* kr = FEK + (size_t)c*D_;
    float acc = 0.f;
    #pragma unroll
    for (int f = 0; f < D_; ++f) acc += q[f]*kr[f];
    lg[j] = acc * 0.125f;
    mx = fmaxf(mx, lg[j]);
  }
  red[tid] = mx; __syncthreads();
  for (int s = 128; s > 0; s >>= 1) { if (tid < s) red[tid] = fmaxf(red[tid], red[tid+s]); __syncthreads(); }
  mx = red[0]; __syncthreads();
  float sum = 0.f;
  #pragma unroll
  for (int j = 0; j < 4; ++j) { lg[j] = __expf(lg[j]-mx); sum += lg[j]; }
  red[tid] = sum; __syncthreads();
  for (int s = 128; s > 0; s >>= 1) { if (tid < s) red[tid] += red[tid+s]; __syncthreads(); }
  float inv = 1.f / red[0];
  #pragma unroll
  for (int j = 0; j < 4; ++j) {
    int c = tid + j*256;
    Acat[(size_t)r*K3_ + (1+g)*N_ + c] = f2b(lg[j]*inv);
  }
}

// ---- K2 (MFMA): [BTN,64] @ Wgcnt^T[64,256] -> G0 row-major + Yt1..3 transposed [bt][d][node]
__global__ __launch_bounds__(256) void k_xw_mfma(
    const float* __restrict__ X, const u16* __restrict__ Wgcnt,
    u16* __restrict__ G0, u16* __restrict__ Yt1, u16* __restrict__ Yt2, u16* __restrict__ Yt3)
{
  __shared__ __align__(16) u16 SM[24576];
  u16* Als = SM;
  u16* Bls = SM + 8192;
  u16* Tls = SM;
  u16* Gls = SM;
  int m0 = blockIdx.x * 128;
  int t = threadIdx.x;
  int w = t >> 6, l = t & 63;

  {
    int rsub = l >> 3, pch = l & 7;
    #pragma unroll
    for (int i = 0; i < 8; ++i) {
      int R0 = w*64 + i*8;
      int n = R0 + rsub;
      int q = pch ^ (n & 7);
      gload_lds16(Wgcnt + (size_t)n*64 + q*8, &Bls[R0*64]);
    }
  }
  #pragma unroll
  for (int i = 0; i < 4; ++i) {
    int flat = t + 256*i;
    int row = flat >> 3, c = flat & 7;
    const float* src = X + (size_t)(m0+row)*64 + c*8;
    float4 f0 = *(const float4*)src;
    float4 f1 = *(const float4*)(src + 4);
    u16x8 pk;
    pk.v[0]=f2b(f0.x); pk.v[1]=f2b(f0.y); pk.v[2]=f2b(f0.z); pk.v[3]=f2b(f0.w);
    pk.v[4]=f2b(f1.x); pk.v[5]=f2b(f1.y); pk.v[6]=f2b(f1.z); pk.v[7]=f2b(f1.w);
    int cs = c ^ (row & 7);
    *(u16x8*)&Als[row*64 + cs*8] = pk;
  }
  __syncthreads();

  int wm = w & 1, wn = w >> 1;
  int lr = l & 15, lk = l >> 4;
  f32x4 acc[4][8] = {};
  #pragma unroll
  for (int ks = 0; ks < 2; ++ks) {
    short8v av[4], bv[8];
    #pragma unroll
    for (int fm = 0; fm < 4; ++fm) {
      int r = wm*64 + fm*16 + lr;
      int ch = (ks*4 + lk) ^ (r & 7);
      av[fm] = *(const short8v*)&Als[r*64 + ch*8];
    }
    #pragma unroll
    for (int fn = 0; fn < 8; ++fn) {
      int n = wn*128 + fn*16 + lr;
      int ch = (ks*4 + lk) ^ (n & 7);
      bv[fn] = *(const short8v*)&Bls[n*64 + ch*8];
    }
    #pragma unroll
    for (int fm = 0; fm < 4; ++fm)
      #pragma unroll
      for (int fn = 0; fn < 8; ++fn)
        acc[fm][fn] = __builtin_amdgcn_mfma_f32_16x16x32_bf16(av[fm], bv[fn], acc[fm][fn], 0, 0, 0);
  }
  __syncthreads();

  #pragma unroll
  for (int fm = 0; fm < 4; ++fm) {
    int row0 = wm*64 + fm*16 + lk*4;
    #pragma unroll
    for (int fn = 0; fn < 8; ++fn) {
      int c = wn*128 + fn*16 + lr;
      if (c >= 64) {
        int dp = c - 64;
        u16x4 pk{ f2b(acc[fm][fn][0]), f2b(acc[fm][fn][1]),
                  f2b(acc[fm][fn][2]), f2b(acc[fm][fn][3]) };
        *(u16x4*)&Tls[dp*128 + (row0 ^ ((dp & 7) << 3))] = pk;
      }
    }
  }
  __syncthreads();
  {
    int bt = m0 >> 10, nb = m0 & 1023;
    #pragma unroll
    for (int i = 0; i < 12; ++i) {
      int cc = t + 256*i;
      int dp = cc >> 4, nc = cc & 15;
      int n0 = nc*8;
      u16x8 vv = *(const u16x8*)&Tls[dp*128 + (n0 ^ ((dp & 7) << 3))];
      int p = dp >> 6, d = dp & 63;
      u16* Yt = (p == 0) ? Yt1 : (p == 1) ? Yt2 : Yt3;
      *(u16x8*)&Yt[((size_t)bt*64 + d)*1024 + nb + n0] = vv;
    }
  }
  __syncthreads();

  if (wn == 0) {
    #pragma unroll
    for (int fm = 0; fm < 4; ++fm) {
      int row0 = wm*64 + fm*16 + lk*4;
      #pragma unroll
      for (int fn = 0; fn < 4; ++fn) {
        int c = fn*16 + lr;
        #pragma unroll
        for (int j = 0; j < 4; ++j) {
          int row = row0 + j;
          Gls[row*64 + (c ^ ((row & 7) << 3))] = f2b(acc[fm][fn][j]);
        }
      }
    }
  }
  __syncthreads();
  #pragma unroll
  for (int i = 0; i < 4; ++i) {
    int cc = t + 256*i;
    int row = cc >> 3, ch = cc & 7;
    u16x8 vv = *(const u16x8*)&Gls[row*64 + ((ch*8) ^ ((row & 7) << 3))];
    *(u16x8*)&G0[(size_t)(m0 + row)*64 + ch*8] = vv;
  }
}

// ---- K3 (MFMA): per bt-pair, C[128 node,128 (2bt x 64 d)] = Acat[128,3072] @ Bstack
// R6 best-measured version: BK=32, 2-buffer, 32 KB LDS, transposed coalesced epilogue.
#define BM 128
#define BK2 32
#define NKT2 (K3_/BK2)   // 96
__global__ __launch_bounds__(256) void k_spatial_mfma(
    const u16* __restrict__ Acat,
    const u16* __restrict__ Yt1, const u16* __restrict__ Yt2, const u16* __restrict__ Yt3,
    const float* __restrict__ bgcn,
    u16* __restrict__ HS)
{
  __shared__ __align__(16) u16 SM[16384];   // 32 KB total
  u16* Als = SM;          // [2][128*32]
  u16* Bls = SM + 8192;   // [2][128*32]

  int f = blockIdx.x + 8*blockIdx.y;
  int u = f & 7, v = f >> 3;
  int btp = u*24 + (v >> 3);
  int m0  = (v & 7) * BM;
  int bt0 = btp * 2;

  int t = threadIdx.x;
  int w = t >> 6, l = t & 63;
  int rsub = l >> 2, pch = l & 3;   // 16 rows x 4 chunks per gload

  f32x4 acc[4][4] = {};
  int wm = w >> 1, wn = w & 1;
  int lr = l & 15, lk = l >> 4;

  // hoisted per-thread staging sources (swizzle: slot p holds logical chunk p ^ ((row>>1)&3))
  const u16* aSrc[2];
  size_t bOff[2];
  #pragma unroll
  for (int i = 0; i < 2; ++i) {
    int row = w*32 + i*16 + rsub;
    int q = pch ^ ((row >> 1) & 3);
    aSrc[i] = Acat + (size_t)(m0 + row)*K3_ + q*8;
    int n = row;
    int qb = pch ^ ((n >> 1) & 3);
    int bt = bt0 + (n >> 6), d = n & 63;
    bOff[i] = ((size_t)bt*64 + d)*1024 + qb*8;
  }

  // prologue stage (kt = 0, plane Yt1)
  #pragma unroll
  for (int i = 0; i < 2; ++i) {
    int R0 = w*32 + i*16;
    gload_lds16(aSrc[i], &Als[R0*32]);
    gload_lds16(Yt1 + bOff[i], &Bls[R0*32]);
  }
  __syncthreads();

  int buf = 0;
  for (int kt = 0; kt < NKT2; ++kt) {
    if (kt + 1 < NKT2) {
      int k0 = (kt + 1) * BK2;
      int pl = k0 >> 10, kk = k0 & 1023;
      const u16* Yt = (pl == 0) ? Yt1 : (pl == 1) ? Yt2 : Yt3;
      int bo = (buf ^ 1) * 4096;
      #pragma unroll
      for (int i = 0; i < 2; ++i) {
        int R0 = w*32 + i*16;
        gload_lds16(aSrc[i] + k0, &Als[bo + R0*32]);
        gload_lds16(Yt + bOff[i] + kk, &Bls[bo + R0*32]);
      }
    }
    const u16* A = Als + buf*4096;
    const u16* Bp = Bls + buf*4096;
    short8v av[4], bv[4];
    #pragma unroll
    for (int fm = 0; fm < 4; ++fm) {
      int r = wm*64 + fm*16 + lr;
      int ch = lk ^ ((r >> 1) & 3);
      av[fm] = *(const short8v*)(A + r*32 + ch*8);
    }
    #pragma unroll
    for (int fn = 0; fn < 4; ++fn) {
      int n = wn*64 + fn*16 + lr;
      int ch = lk ^ ((n >> 1) & 3);
      bv[fn] = *(const short8v*)(Bp + n*32 + ch*8);
    }
    #pragma unroll
    for (int fm = 0; fm < 4; ++fm)
      #pragma unroll
      for (int fn = 0; fn < 4; ++fn)
        acc[fm][fn] = __builtin_amdgcn_mfma_f32_16x16x32_bf16(av[fm], bv[fn], acc[fm][fn], 0, 0, 0);
    __syncthreads();
    buf ^= 1;
  }

  // ---- epilogue: acc -> LDS transpose tile [128 node][128 col] (bf16, XOR-swizzled)
  u16* Tls = SM;   // 128*128 = 16384 u16 = entire LDS
  #pragma unroll
  for (int fm = 0; fm < 4; ++fm) {
    #pragma unroll
    for (int fn = 0; fn < 4; ++fn) {
      int col = wn*64 + fn*16 + lr;
      int cc = col >> 3, cw = col & 7;
      #pragma unroll
      for (int j = 0; j < 4; ++j) {
        int node = wm*64 + fm*16 + lk*4 + j;
        int sc = cc ^ (node & 7);
        Tls[node*128 + sc*8 + cw] = f2b(acc[fm][fn][j]);
      }
    }
  }
  __syncthreads();
  // coalesced RMW: HS = relu(Z + G0 + bgcn), u16x8 granularity
  #pragma unroll
  for (int i = 0; i < 8; ++i) {
    int flat = t + 256*i;
    int node = flat >> 4, cc = flat & 15;
    int sc = cc ^ (node & 7);
    u16x8 zv = *(const u16x8*)&Tls[node*128 + sc*8];
    int bt = bt0 + (cc >> 3), d0 = (cc & 7)*8;
    size_t idx = ((size_t)bt*N_ + (m0 + node))*64 + d0;
    u16x8 gv = *(const u16x8*)&HS[idx];
    float4 b0 = *(const float4*)&bgcn[d0];
    float4 b1 = *(const float4*)&bgcn[d0 + 4];
    float bb[8] = { b0.x, b0.y, b0.z, b0.w, b1.x, b1.y, b1.z, b1.w };
    u16x8 ov;
    #pragma unroll
    for (int e = 0; e < 8; ++e) {
      float vv2 = b2f(zv.v[e]) + b2f(gv.v[e]) + bb[e];
      ov.v[e] = f2b(fmaxf(vv2, 0.f));
    }
    *(u16x8*)&HS[idx] = ov;
  }
}

// ---- K4a (MFMA): qkv = relu([X|STE] @ Wqkv^T + b) -> q,k,v bf16 [BTN][64]
__global__ __launch_bounds__(256) void k_qkv(
    const float* __restrict__ X, const float* __restrict__ STE,
    const u16* __restrict__ Wqkvt,
    const float* __restrict__ bq, const float* __restrict__ bk, const float* __restrict__ bv,
    u16* __restrict__ qb, u16* __restrict__ kb, u16* __restrict__ vb)
{
  __shared__ __align__(16) u16 Als[128*128];   // [row][k], chunk-swizzled
  __shared__ __align__(16) u16 Bls[192*128];   // W^T [n][k], chunk-swizzled
  int m0 = blockIdx.x * 128;
  int t = threadIdx.x;
  int w = t >> 6, l = t & 63;

  {
    int rsub = l >> 4, pch = l & 15;
    #pragma unroll
    for (int i = 0; i < 12; ++i) {
      int R0 = w*48 + i*4;
      int n = R0 + rsub;
      int sq = pch ^ (n & 7);
      gload_lds16(Wqkvt + (size_t)n*128 + sq*8, &Bls[R0*128]);
    }
  }
  #pragma unroll
  for (int i = 0; i < 8; ++i) {
    int flat = t + 256*i;
    int row = flat >> 4, c = flat & 15;
    const float* src = ((c < 8) ? X : STE) + (size_t)(m0+row)*64 + (c & 7)*8;
    float4 f0 = *(const float4*)src;
    float4 f1 = *(const float4*)(src + 4);
    u16x8 pk;
    pk.v[0]=f2b(f0.x); pk.v[1]=f2b(f0.y); pk.v[2]=f2b(f0.z); pk.v[3]=f2b(f0.w);
    pk.v[4]=f2b(f1.x); pk.v[5]=f2b(f1.y); pk.v[6]=f2b(f1.z); pk.v[7]=f2b(f1.w);
    int cs = c ^ (row & 7);
    *(u16x8*)&Als[row*128 + cs*8] = pk;
  }
  __syncthreads();

  int wm = w >> 1, wn = w & 1;
  int lr = l & 15, lk = l >> 4;
  f32x4 acc[4][6] = {};
  #pragma unroll
  for (int ks = 0; ks < 4; ++ks) {
    short8v av[4], bvv[6];
    #pragma unroll
    for (int fm = 0; fm < 4; ++fm) {
      int r = wm*64 + fm*16 + lr;
      int ch = (ks*4 + lk) ^ (r & 7);
      av[fm] = *(const short8v*)&Als[r*128 + ch*8];
    }
    #pragma unroll
    for (int fn = 0; fn < 6; ++fn) {
      int n = wn*96 + fn*16 + lr;
      int ch = (ks*4 + lk) ^ (n & 7);
      bvv[fn] = *(const short8v*)&Bls[n*128 + ch*8];
    }
    #pragma unroll
    for (int fm = 0; fm < 4; ++fm)
      #pragma unroll
      for (int fn = 0; fn < 6; ++fn)
        acc[fm][fn] = __builtin_amdgcn_mfma_f32_16x16x32_bf16(av[fm], bvv[fn], acc[fm][fn], 0, 0, 0);
  }

  #pragma unroll
  for (int fm = 0; fm < 4; ++fm) {
    int rowb = m0 + wm*64 + fm*16 + lk*4;
    #pragma unroll
    for (int fn = 0; fn < 6; ++fn) {
      int col = wn*96 + fn*16 + lr;
      int sel = col >> 6, d = col & 63;
      u16* dst = (sel == 0) ? qb : (sel == 1) ? kb : vb;
      float bias = ((sel == 0) ? bq : (sel == 1) ? bk : bv)[d];
      #pragma unroll
      for (int j = 0; j < 4; ++j) {
        float val = acc[fm][fn][j] + bias;
        dst[(size_t)(rowb + j)*64 + d] = f2b(fmaxf(val, 0.f));
      }
    }
  }
}

// ---- K4b (fused): attention (register path) + HT = relu(o@Wx1+bx1)@Wx2+bx2 in one kernel.
// 4 waves = 4 (b,n) pairs per block; o lives only in LDS (48x64 tile); HT overwrites q rows
// (safe: each block reads exactly its own q rows before writing them; blocks are row-disjoint).
__global__ __launch_bounds__(256) void k_attn_ht(
    const u16* __restrict__ qb, const u16* __restrict__ kb, const u16* __restrict__ vb,
    const u16* __restrict__ W1t, const u16* __restrict__ W2t,
    const float* __restrict__ bx1, const float* __restrict__ bx2,
    u16* __restrict__ HT)
{
  __shared__ __align__(16) u16 Ols[48*64];    // 6 KB
  __shared__ __align__(16) u16 H1ls[48*64];   // 6 KB
  __shared__ __align__(16) u16 W1ls[64*64];   // 8 KB
  __shared__ __align__(16) u16 W2ls[64*64];   // 8 KB
  int t = threadIdx.x;
  int w = t >> 6, l = t & 63;

  // stage W1t/W2t (pre-swizzled source; k_ht's proven pattern)
  {
    int rsub = l >> 3, pch = l & 7;
    #pragma unroll
    for (int i = 0; i < 2; ++i) {
      int R0 = w*16 + i*8;
      int row = R0 + rsub;
      int sq = pch ^ (row & 7);
      gload_lds16(W1t + (size_t)row*64 + sq*8, &W1ls[R0*64]);
      gload_lds16(W2t + (size_t)row*64 + sq*8, &W2ls[R0*64]);
    }
  }

  // ---- attention: one wave per (b,n)
  int flat = blockIdx.x*4 + w;
  int b = flat >> 10, n = flat & 1023;
  float qv[T_], kv[T_], vv[T_];
  #pragma unroll
  for (int tt = 0; tt < T_; ++tt) {
    size_t idx = ((size_t)(b*T_ + tt)*N_ + n)*64 + l;
    qv[tt] = b2f(qb[idx]); kv[tt] = b2f(kb[idx]); vv[tt] = b2f(vb[idx]);
  }
  #pragma unroll
  for (int tt = 0; tt < T_; ++tt) {
    float sc[T_];
    float mx = -1e30f;
    #pragma unroll
    for (int j = 0; j < T_; ++j) {
      float p = qv[tt]*kv[j];
      p += __shfl_xor(p, 1);
      p += __shfl_xor(p, 2);
      p += __shfl_xor(p, 4);
      sc[j] = p * 0.3535533906f;
      mx = fmaxf(mx, sc[j]);
    }
    float sum = 0.f;
    #pragma unroll
    for (int j = 0; j < T_; ++j) { sc[j] = __expf(sc[j]-mx); sum += sc[j]; }
    float o = 0.f;
    #pragma unroll
    for (int j = 0; j < T_; ++j) o += sc[j]*vv[j];
    int row = w*T_ + tt;
    Ols[row*64 + ((l >> 3) ^ (row & 7))*8 + (l & 7)] = f2b(o / sum);
  }
  __syncthreads();   // drains gload_lds too (vmcnt(0) before barrier)

  // ---- GEMM1: H1 = relu(O @ Wx1 + bx1); 48 rows, wave w owns cols w*16..w*16+15
  int lr = l & 15, lk = l >> 4;
  int col = w*16 + lr;
  f32x4 acc1[3] = {};
  #pragma unroll
  for (int ks = 0; ks < 2; ++ks) {
    short8v av[3], bvv;
    #pragma unroll
    for (int fm = 0; fm < 3; ++fm) {
      int r = fm*16 + lr;
      int ch = (ks*4 + lk) ^ (r & 7);
      av[fm] = *(const short8v*)&Ols[r*64 + ch*8];
    }
    {
      int nn = w*16 + lr;
      int ch = (ks*4 + lk) ^ (nn & 7);
      bvv = *(const short8v*)&W1ls[nn*64 + ch*8];
    }
    #pragma unroll
    for (int fm = 0; fm < 3; ++fm)
      acc1[fm] = __builtin_amdgcn_mfma_f32_16x16x32_bf16(av[fm], bvv, acc1[fm], 0, 0, 0);
  }
  {
    float bias1 = bx1[col];
    #pragma unroll
    for (int fm = 0; fm < 3; ++fm)
      #pragma unroll
      for (int j = 0; j < 4; ++j) {
        int r = fm*16 + lk*4 + j;
        H1ls[r*64 + ((col >> 3) ^ (r & 7))*8 + (col & 7)] = f2b(fmaxf(acc1[fm][j] + bias1, 0.f));
      }
  }
  __syncthreads();

  // ---- GEMM2: HT = H1 @ Wx2 + bx2
  f32x4 acc2[3] = {};
  #pragma unroll
  for (int ks = 0; ks < 2; ++ks) {
    short8v av[3], bvv;
    #pragma unroll
    for (int fm = 0; fm < 3; ++fm) {
      int r = fm*16 + lr;
      int ch = (ks*4 + lk) ^ (r & 7);
      av[fm] = *(const short8v*)&H1ls[r*64 + ch*8];
    }
    {
      int nn = w*16 + lr;
      int ch = (ks*4 + lk) ^ (nn & 7);
      bvv = *(const short8v*)&W2ls[nn*64 + ch*8];
    }
    #pragma unroll
    for (int fm = 0; fm < 3; ++fm)
      acc2[fm] = __builtin_amdgcn_mfma_f32_16x16x32_bf16(av[fm], bvv, acc2[fm], 0, 0, 0);
  }
  {
    float bias2 = bx2[col];
    #pragma unroll
    for (int fm = 0; fm < 3; ++fm)
      #pragma unroll
      for (int j = 0; j < 4; ++j) {
        int r = fm*16 + lk*4 + j;
        int fp = blockIdx.x*4 + (r / T_);
        int tt = r % T_;
        int b2 = fp >> 10, n2 = fp & 1023;
        HT[((size_t)(b2*T_ + tt)*N_ + n2)*64 + col] = f2b(acc2[fm][j] + bias2);
      }
  }
}

// ---- K5 (MFMA): gated fusion + output head, 128 rows/block, all-LDS chain
__global__ __launch_bounds__(256) void k_fusion_mfma(
    const float* __restrict__ X,
    const u16* __restrict__ HS, const u16* __restrict__ HT,
    const u16* __restrict__ Wstt, const u16* __restrict__ Wh1t, const u16* __restrict__ Wh2t,
    const float* __restrict__ btb, const float* __restrict__ bh1, const float* __restrict__ bh2,
    float* __restrict__ out)
{
  __shared__ __align__(16) u16 Als[128*128];
  __shared__ __align__(16) u16 Wst[64*128];
  __shared__ __align__(16) u16 W1ls[64*64];
  __shared__ __align__(16) u16 W2ls[64*64];
  __shared__ __align__(16) u16 Hls[128*64];
  int m0 = blockIdx.x * 128;
  int t = threadIdx.x;
  int w = t >> 6, l = t & 63;

  {
    int rsub = l >> 4, pch = l & 15;
    #pragma unroll
    for (int i = 0; i < 8; ++i) {
      int R0 = w*32 + i*4;
      int row = R0 + rsub;
      int q = pch ^ (row & 7);
      const u16* src = (q < 8) ? (HS + (size_t)(m0 + row)*64 + q*8)
                               : (HT + (size_t)(m0 + row)*64 + (q - 8)*8);
      gload_lds16(src, &Als[R0*128]);
    }
    #pragma unroll
    for (int i = 0; i < 4; ++i) {
      int R0 = w*16 + i*4;
      int n = R0 + rsub;
      int q = pch ^ (n & 7);
      gload_lds16(Wstt + (size_t)n*128 + q*8, &Wst[R0*128]);
    }
  }
  {
    int rsub = l >> 3, pch = l & 7;
    #pragma unroll
    for (int i = 0; i < 2; ++i) {
      int R0 = w*16 + i*8;
      int row = R0 + rsub;
      int q = pch ^ (row & 7);
      gload_lds16(Wh1t + (size_t)row*64 + q*8, &W1ls[R0*64]);
      gload_lds16(Wh2t + (size_t)row*64 + q*8, &W2ls[R0*64]);
    }
  }
  __syncthreads();

  int lr = l & 15, lk = l >> 4;
  f32x4 acc1[2][4] = {};
  #pragma unroll
  for (int ks = 0; ks < 4; ++ks) {
    short8v av[2], bvv[4];
    #pragma unroll
    for (int fm = 0; fm < 2; ++fm) {
      int r = w*32 + fm*16 + lr;
      int ch = (ks*4 + lk) ^ (r & 7);
      av[fm] = *(const short8v*)&Als[r*128 + ch*8];
    }
    #pragma unroll
    for (int fn = 0; fn < 4; ++fn) {
      int n = fn*16 + lr;
      int ch = (ks*4 + lk) ^ (n & 7);
      bvv[fn] = *(const short8v*)&Wst[n*128 + ch*8];
    }
    #pragma unroll
    for (int fm = 0; fm < 2; ++fm)
      #pragma unroll
      for (int fn = 0; fn < 4; ++fn)
        acc1[fm][fn] = __builtin_amdgcn_mfma_f32_16x16x32_bf16(av[fm], bvv[fn], acc1[fm][fn], 0, 0, 0);
  }
  #pragma unroll
  for (int fm = 0; fm < 2; ++fm) {
    #pragma unroll
    for (int fn = 0; fn < 4; ++fn) {
      int col = fn*16 + lr;
      float bb = btb[col];
      #pragma unroll
      for (int j = 0; j < 4; ++j) {
        int row = w*32 + fm*16 + lk*4 + j;
        float a_s = acc1[fm][fn][j] + bb;
        float zg = 1.f/(1.f + __expf(-a_s));
        int cs = (col >> 3) ^ (row & 7);
        float hs = b2f(Als[row*128 + cs*8 + (col & 7)]);
        float ht = b2f(Als[row*128 + (cs + 8)*8 + (col & 7)]);
        float H = zg*hs + (1.f - zg)*ht;
        Hls[row*64 + cs*8 + (col & 7)] = f2b(H);
      }
    }
  }
  __syncthreads();

  u16* H2ls = Wst;
  f32x4 acc2[2][4] = {};
  #pragma unroll
  for (int ks = 0; ks < 2; ++ks) {
    short8v av[2], bvv[4];
    #pragma unroll
    for (int fm = 0; fm < 2; ++fm) {
      int r = w*32 + fm*16 + lr;
      int ch = (ks*4 + lk) ^ (r & 7);
      av[fm] = *(const short8v*)&Hls[r*64 + ch*8];
    }
    #pragma unroll
    for (int fn = 0; fn < 4; ++fn) {
      int n = fn*16 + lr;
      int ch = (ks*4 + lk) ^ (n & 7);
      bvv[fn] = *(const short8v*)&W1ls[n*64 + ch*8];
    }
    #pragma unroll
    for (int fm = 0; fm < 2; ++fm)
      #pragma unroll
      for (int fn = 0; fn < 4; ++fn)
        acc2[fm][fn] = __builtin_amdgcn_mfma_f32_16x16x32_bf16(av[fm], bvv[fn], acc2[fm][fn], 0, 0, 0);
  }
  __syncthreads();
  #pragma unroll
  for (int fm = 0; fm < 2; ++fm) {
    #pragma unroll
    for (int fn = 0; fn < 4; ++fn) {
      int col = fn*16 + lr;
      float bias = bh1[col];
      #pragma unroll
      for (int j = 0; j < 4; ++j) {
        int row = w*32 + fm*16 + lk*4 + j;
        float val = acc2[fm][fn][j] + bias;
        int cs = (col >> 3) ^ (row & 7);
        H2ls[row*64 + cs*8 + (col & 7)] = f2b(fmaxf(val, 0.f));
      }
    }
  }
  __syncthreads();

  f32x4 acc3[2][4] = {};
  #pragma unroll
  for (int ks = 0; ks < 2; ++ks) {
    short8v av[2], bvv[4];
    #pragma unroll
    for (int fm = 0; fm < 2; ++fm) {
      int r = w*32 + fm*16 + lr;
      int ch = (ks*4 + lk) ^ (r & 7);
      av[fm] = *(const short8v*)&H2ls[r*64 + ch*8];
    }
    #pragma unroll
    for (int fn = 0; fn < 4; ++fn) {
      int n = fn*16 + lr;
      int ch = (ks*4 + lk) ^ (n & 7);
      bvv[fn] = *(const short8v*)&W2ls[n*64 + ch*8];
    }
    #pragma unroll
    for (int fm = 0; fm < 2; ++fm)
      #pragma unroll
      for (int fn = 0; fn < 4; ++fn)
        acc3[fm][fn] = __builtin_amdgcn_mfma_f32_16x16x32_bf16(av[fm], bvv[fn], acc3[fm][fn], 0, 0, 0);
  }
  #pragma unroll
  for (int fm = 0; fm < 2; ++fm) {
    #pragma unroll
    for (int fn = 0; fn < 4; ++fn) {
      int col = fn*16 + lr;
      float bias = bh2[col];
      #pragma unroll
      for (int j = 0; j < 4; ++j) {
        int row = w*32 + fm*16 + lk*4 + j;
        size_t gi = (size_t)(m0 + row)*64 + col;
        out[gi] = X[gi] + acc3[fm][fn][j] + bias;
      }
    }
  }
}

extern "C" void kernel_launch(void* const* d_in, const int* in_sizes, int n_in,
                              void* d_out, int out_size, void* d_ws, size_t ws_size,
                              hipStream_t stream) {
  const float* X    = (const float*)d_in[0];
  const float* STE  = (const float*)d_in[1];
  const float* adj  = (const float*)d_in[2];
  const float* feat0= (const float*)d_in[3];
  const float* feat1= (const float*)d_in[4];
  const float* Wq0  = (const float*)d_in[5];
  const float* Wk0  = (const float*)d_in[6];
  const float* Wq1  = (const float*)d_in[7];
  const float* Wk1  = (const float*)d_in[8];
  const float* Wgcn = (const float*)d_in[9];
  const float* bgcn = (const float*)d_in[10];
  const float* Wq   = (const float*)d_in[11];
  const float* bq   = (const float*)d_in[12];
  const float* Wk   = (const float*)d_in[13];
  const float* bk   = (const float*)d_in[14];
  const float* Wv   = (const float*)d_in[15];
  const float* bv   = (const float*)d_in[16];
  const float* Wx1  = (const float*)d_in[17];
  const float* bx1  = (const float*)d_in[18];
  const float* Wx2  = (const float*)d_in[19];
  const float* bx2  = (const float*)d_in[20];
  const float* Ws   = (const float*)d_in[21];
  const float* Wt   = (const float*)d_in[22];
  const float* btb  = (const float*)d_in[23];
  const float* Wh1  = (const float*)d_in[24];
  const float* bh1  = (const float*)d_in[25];
  const float* Wh2  = (const float*)d_in[26];
  const float* bh2  = (const float*)d_in[27];
  (void)in_sizes; (void)n_in; (void)out_size;

  // ws layout: see R5 comment (unchanged); o-buffer no longer used.
  const size_t NEEDED = 164626432ull;
  if (ws_size < NEEDED) return;

  char* w = (char*)d_ws;
  float* fe    = (float*)(w);
  u16*   Acat  = (u16*)(w + 1048576);
  u16*   Wqkvt = (u16*)(w + 7340032);
  u16*   W1t   = (u16*)(w + 7389184);
  u16*   W2t   = (u16*)(w + 7397376);
  u16*   Wstt  = (u16*)(w + 7405568);
  u16*   Wh1t  = (u16*)(w + 7421952);
  u16*   Wh2t  = (u16*)(w + 7430144);
  u16*   Wgcnt = (u16*)(w + 7438336);
  u16*   Yt2   = (u16*)(w + 13631488);
  u16*   Yt3   = (u16*)(w + 63963136);
  u16*   HSb   = (u16*)(w + 114294784);
  u16*   Yt1   = (u16*)d_out;
  u16*   qb    = Yt2;
  u16*   kbuf  = Yt3;
  u16*   vbuf  = (u16*)d_out;
  u16*   HTb   = Yt2;   // HT overwrites q in place (per-block read-before-write, rows disjoint)

  k_fe<<<dim3(N_, 4), 64, 0, stream>>>(feat0, feat1, Wq0, Wk0, Wq1, Wk1, fe);
  k_adjcopy<<<N_, 256, 0, stream>>>(adj, Acat);
  k_prep<<<64, 256, 0, stream>>>(Wq, Wk, Wv, Wx1, Wx2, Ws, Wt, Wh1, Wh2, Wgcn,
                                 Wqkvt, W1t, W2t, Wstt, Wh1t, Wh2t, Wgcnt);
  k_graph_softmax<<<dim3(N_, 2), 256, 0, stream>>>(fe, Acat);
  k_xw_mfma<<<NROWS_/128, 256, 0, stream>>>(X, Wgcnt, HSb, Yt1, Yt2, Yt3);
  k_spatial_mfma<<<dim3(8, BT_/2), 256, 0, stream>>>(Acat, Yt1, Yt2, Yt3, bgcn, HSb);
  k_qkv<<<NROWS_/128, 256, 0, stream>>>(X, STE, Wqkvt, bq, bk, bv, qb, kbuf, vbuf);
  k_attn_ht<<<(B_*N_)/4, 256, 0, stream>>>(qb, kbuf, vbuf, W1t, W2t, bx1, bx2, HTb);
  k_fusion_mfma<<<NROWS_/128, 256, 0, stream>>>(X, HSb, HTb, Wstt, Wh1t, Wh2t,
                                                btb, bh1, bh2, (float*)d_out);
}